// Round 8
// baseline (745.980 us; speedup 1.0000x reference)
//
#include <hip/hip_runtime.h>
#include <hip/hip_bf16.h>

typedef unsigned short u16;
typedef unsigned int u32;
typedef __attribute__((ext_vector_type(8))) short bf16x8;
typedef __attribute__((ext_vector_type(4))) float f32x4;
typedef __attribute__((ext_vector_type(4))) u32 u32x4;

#define BATCH 16384
#define NLEVS 60

#define SFC_OFF ((size_t)BATCH * NLEVS * 4)
#define MEM_OFF (SFC_OFF + (size_t)BATCH * 3)

// packed u16 plane offsets (in u16 units, from wpk) — layout validated r5-r7
#define W1IH_HI 0
#define W1IH_LO 8192
#define W1HH_HI 16384
#define W1HH_LO 32768
#define W2IH_HI 49152
#define W2IH_LO 65536
#define W2HH_HI 81920
#define W2HH_LO 98304
#define WHD_HI  114688
#define WHD_LO  116736

#define WPK_BYTE_OFF 4096
#define WS_R1_BYTE_OFF 262144

// gate prescale: i,f,o by -log2(e) (sigmoid), g by +2*log2(e) (tanh)
#define SIGK -1.4426950408889634f
#define TANK  2.8853900817779268f

#define MFMA(a, b, c) __builtin_amdgcn_mfma_f32_16x16x32_bf16((a), (b), (c), 0, 0, 0)

__device__ __forceinline__ float bf2f(u16 u) {
    union { u32 i; float f; } v; v.i = (u32)u << 16; return v.f;
}
__device__ __forceinline__ u16 f2bf(float f) {
    __hip_bfloat16 b = __float2bfloat16(f);
    u16 u; __builtin_memcpy(&u, &b, 2); return u;
}
__device__ __forceinline__ void split2(float w, u16& hi, u16& lo) {
    u16 h = f2bf(w);
    hi = h;
    lo = f2bf(w - bf2f(h));
}
__device__ __forceinline__ float tanh_(float x) {      // plain tanh (inits/heads)
    float ax = fabsf(x);
    float e  = __builtin_amdgcn_exp2f(-TANK * ax);
    float t  = (1.0f - e) * __builtin_amdgcn_rcpf(1.0f + e);
    return copysignf(t, x);
}

// LDS swizzles — single definition used by BOTH stager and reader.
__device__ __forceinline__ int swz32(int c, int q4) { return c * 64 + ((q4 * 16) ^ ((c & 3) << 4)); }
__device__ __forceinline__ int swz64(int c, int qk) { return c * 128 + ((qk * 16) ^ ((c & 7) << 4)); }

// Pack all weights to bf16 hi/lo planes with gate prescale; fuse biases and
// Wout@Wlat head (heads unscaled).
__global__ void setup_pack(const float* __restrict__ W1ih, const float* __restrict__ W1hh,
                           const float* __restrict__ W2ih, const float* __restrict__ W2hh,
                           const float* __restrict__ Wlat, const float* __restrict__ Wout,
                           const float* __restrict__ Wsfco,
                           const float* __restrict__ b1ih, const float* __restrict__ b1hh,
                           const float* __restrict__ b2ih, const float* __restrict__ b2hh,
                           const float* __restrict__ blat, const float* __restrict__ bout,
                           const float* __restrict__ bsfco,
                           float* __restrict__ wsf, u16* __restrict__ wpk)
{
    int t = blockIdx.x * 256 + threadIdx.x;
    if (t < 256) {
        float sc = ((t >> 6) == 2) ? TANK : SIGK;
        wsf[t] = (b1ih[t] + b1hh[t]) * sc; return;
    }
    if (t < 512) {
        int j = t - 256;
        float sc = ((j >> 6) == 2) ? TANK : SIGK;
        wsf[256 + j] = (b2ih[j] + b2hh[j]) * sc; return;
    }
    if (t < 544) {
        int j = t - 512; float v;
        if (j < 16) v = blat[j];
        else if (j < 20) { v = bout[j - 16]; for (int m = 0; m < 16; ++m) v += Wout[(j - 16) * 16 + m] * blat[m]; }
        else if (j < 23) v = bsfco[j - 20];
        else v = 0.f;
        wsf[512 + j] = v; return;
    }
    int u = t - 544;
    float w; int hi_off, lo_off, idx, gate = -1;
    if (u < 8192) {
        int col = u >> 5, k = u & 31;
        w = (k < 20) ? W1ih[col * 20 + k] : 0.f;
        hi_off = W1IH_HI; lo_off = W1IH_LO; idx = u; gate = col >> 6;
    } else if (u < 24576) {
        idx = u - 8192; w = W1hh[idx]; hi_off = W1HH_HI; lo_off = W1HH_LO; gate = idx >> 12;
    } else if (u < 40960) {
        idx = u - 24576; w = W2ih[idx]; hi_off = W2IH_HI; lo_off = W2IH_LO; gate = idx >> 12;
    } else if (u < 57344) {
        idx = u - 40960; w = W2hh[idx]; hi_off = W2HH_HI; lo_off = W2HH_LO; gate = idx >> 12;
    } else if (u < 59392) {
        idx = u - 57344; int hc = idx >> 6, k = idx & 63;
        if (hc < 16) w = Wlat[hc * 64 + k];
        else if (hc < 20) { w = 0.f; for (int m = 0; m < 16; ++m) w += Wout[(hc - 16) * 16 + m] * Wlat[m * 64 + k]; }
        else if (hc < 23) w = Wsfco[(hc - 20) * 64 + k];
        else w = 0.f;
        hi_off = WHD_HI; lo_off = WHD_LO;
    } else return;
    if (gate >= 0) w *= (gate == 2) ? TANK : SIGK;
    u16 h_, l_; split2(w, h_, l_);
    wpk[hi_off + idx] = h_;
    wpk[lo_off + idx] = l_;
}

// Fused gate epilogue: inputs are PRESCALED gate pre-activations.
// si,sf,so = -log2e * x ; sg = 2*log2e * g. Updates c, returns h.
__device__ __forceinline__ float gate_act(float si, float sf, float sg, float so, float& c) {
    float ei = __builtin_amdgcn_exp2f(si);
    float ef = __builtin_amdgcn_exp2f(sf);
    float eo = __builtin_amdgcn_exp2f(so);
    float eg = __builtin_amdgcn_exp2f(-fabsf(sg));
    // sigm(i)*tanh(g) = copysign(1-eg, g) * rcp((1+ei)(1+eg))
    float p2 = copysignf(1.f - eg, sg) * __builtin_amdgcn_rcpf((1.f + ei) * (1.f + eg));
    c = fmaf(__builtin_amdgcn_rcpf(1.f + ef), c, p2);
    float ec = __builtin_amdgcn_exp2f(-fabsf(TANK * c));
    return copysignf(1.f - ec, c) * __builtin_amdgcn_rcpf((1.f + eo) * (1.f + ec));
}

// ============ Kernel 1: LSTM1 over reversed levels ============
// 512 thr = 8 waves x 8 real rows (A rows 8-15 duplicate 0-7). One weight copy
// in LDS shared by 8 waves -> 2 waves/SIMD. One barrier total.
#define K1_IH_H 0
#define K1_IH_L 16384
#define K1_HH_H 32768
#define K1_HH_L 65536
#define K1_HB   98304
__global__ __launch_bounds__(512, 1)
void lstm1_kern(const float* __restrict__ in_main, const float* __restrict__ in_aux,
                const float* __restrict__ in_mem,
                const float* __restrict__ Wsfc1, const float* __restrict__ bsfc1,
                const float* __restrict__ Wsfc2, const float* __restrict__ bsfc2,
                const float* __restrict__ wsf, const u16* __restrict__ wpk,
                u16* __restrict__ r1h, u16* __restrict__ r1l,
                int b_off, int ch_rows)
{
    __shared__ __align__(16) char s[116736];
    const int tid = threadIdx.x;
    for (int i = tid; i < 1024; i += 512) {
        int c = i >> 2, q4 = i & 3;
        *(u32x4*)(s + K1_IH_H + swz32(c, q4)) = *(const u32x4*)(wpk + W1IH_HI + c * 32 + q4 * 8);
        *(u32x4*)(s + K1_IH_L + swz32(c, q4)) = *(const u32x4*)(wpk + W1IH_LO + c * 32 + q4 * 8);
    }
    for (int i = tid; i < 2048; i += 512) {
        int c = i >> 3, qk = i & 7;
        *(u32x4*)(s + K1_HH_H + swz64(c, qk)) = *(const u32x4*)(wpk + W1HH_HI + c * 64 + qk * 8);
        *(u32x4*)(s + K1_HH_L + swz64(c, qk)) = *(const u32x4*)(wpk + W1HH_LO + c * 64 + qk * 8);
    }
    __syncthreads();   // the ONLY barrier; LDS weights read-only below

    const int lane = tid & 63, wv = tid >> 6;
    const int q = lane >> 4, l15 = lane & 15;
    const int lloc = blockIdx.x * 64 + wv * 8 + (l15 & 7);  // chunk-local row (dup l15>=8)
    const int aRow = b_off + lloc;
    const int crow = b_off + blockIdx.x * 64 + wv * 8 + q * 4;  // valid rows only q<2
    u32* hb = (u32*)(s + K1_HB) + wv * 576;   // wave-private 8x72 u32

    bf16x8 hfh[2], hfl[2];
    float cst[4][4];
    float b1r[4][4];
#pragma unroll
    for (int g = 0; g < 4; ++g)
#pragma unroll
        for (int nt = 0; nt < 4; ++nt)
            b1r[g][nt] = wsf[g * 64 + nt * 16 + l15];

    // init h0 (A-frag layout, row aRow) and c0 (C-layout, rows crow+r for q<2)
    {
        const float a0 = in_aux[(size_t)aRow * 3];
        const float a1 = in_aux[(size_t)aRow * 3 + 1];
        const float a2 = in_aux[(size_t)aRow * 3 + 2];
#pragma unroll
        for (int kt = 0; kt < 2; ++kt) {
            u32 dh[4], dl[4];
#pragma unroll
            for (int p = 0; p < 4; ++p) {
                int k0 = kt * 32 + q * 8 + p * 2;
                float ha = tanh_(fmaf(a0, Wsfc1[k0*3], fmaf(a1, Wsfc1[k0*3+1], fmaf(a2, Wsfc1[k0*3+2], bsfc1[k0]))));
                float hbv = tanh_(fmaf(a0, Wsfc1[k0*3+3], fmaf(a1, Wsfc1[k0*3+4], fmaf(a2, Wsfc1[k0*3+5], bsfc1[k0+1]))));
                u16 hah, hal, hbh, hbl; split2(ha, hah, hal); split2(hbv, hbh, hbl);
                dh[p] = ((u32)hbh << 16) | hah;
                dl[p] = ((u32)hbl << 16) | hal;
            }
            __builtin_memcpy(&hfh[kt], dh, 16);
            __builtin_memcpy(&hfl[kt], dl, 16);
        }
#pragma unroll
        for (int r = 0; r < 4; ++r) {
            int cr = crow + r; if (cr > BATCH - 1) cr = BATCH - 1;   // clamp (q>=2 lanes)
            const size_t gr = (size_t)cr * 3;
            float c0 = in_aux[gr], c1 = in_aux[gr + 1], c2 = in_aux[gr + 2];
#pragma unroll
            for (int nt = 0; nt < 4; ++nt) {
                int u = nt * 16 + l15;
                cst[nt][r] = tanh_(fmaf(c0, Wsfc2[u*3], fmaf(c1, Wsfc2[u*3+1], fmaf(c2, Wsfc2[u*3+2], bsfc2[u]))));
            }
        }
    }

    // x prefetch (lev 59)
    float4 XA = {0,0,0,0}, XB = {0,0,0,0};
    {
        const size_t mi = (size_t)aRow * NLEVS + 59;
        if (q == 0)      { XA = *(const float4*)(in_main + mi * 4);      XB = *(const float4*)(in_mem + mi * 16); }
        else if (q == 1) { XA = *(const float4*)(in_mem + mi * 16 + 4);  XB = *(const float4*)(in_mem + mi * 16 + 8); }
        else if (q == 2) { XA = *(const float4*)(in_mem + mi * 16 + 12); }
    }

#pragma unroll 1
    for (int t = 0; t < NLEVS; ++t) {
        const int lev = 59 - t;
        bf16x8 axh, axl;
        {
            float xv[8] = {0, 0, 0, 0, 0, 0, 0, 0};
            if (q < 2)       { xv[0]=XA.x; xv[1]=XA.y; xv[2]=XA.z; xv[3]=XA.w; xv[4]=XB.x; xv[5]=XB.y; xv[6]=XB.z; xv[7]=XB.w; }
            else if (q == 2) { xv[0]=XA.x; xv[1]=XA.y; xv[2]=XA.z; xv[3]=XA.w; }
            u32 dh[4], dl[4];
#pragma unroll
            for (int p = 0; p < 4; ++p) {
                u16 h0, l0, h1, l1; split2(xv[p*2], h0, l0); split2(xv[p*2+1], h1, l1);
                dh[p] = ((u32)h1 << 16) | h0;
                dl[p] = ((u32)l1 << 16) | l0;
            }
            __builtin_memcpy(&axh, dh, 16);
            __builtin_memcpy(&axl, dl, 16);
        }
        if (t < 59) {
            const size_t mi = (size_t)aRow * NLEVS + (lev - 1);
            if (q == 0)      { XA = *(const float4*)(in_main + mi * 4);      XB = *(const float4*)(in_mem + mi * 16); }
            else if (q == 1) { XA = *(const float4*)(in_mem + mi * 16 + 4);  XB = *(const float4*)(in_mem + mi * 16 + 8); }
            else if (q == 2) { XA = *(const float4*)(in_mem + mi * 16 + 12); }
        }
#pragma unroll
        for (int nt = 0; nt < 4; ++nt) {
            f32x4 C[4];
#pragma unroll
            for (int g = 0; g < 4; ++g) {
                const int col = g * 64 + nt * 16 + l15;
                const bf16x8 Bih = *(const bf16x8*)(s + K1_IH_H + swz32(col, q));
                const bf16x8 Bil = *(const bf16x8*)(s + K1_IH_L + swz32(col, q));
                f32x4 a = {b1r[g][nt], b1r[g][nt], b1r[g][nt], b1r[g][nt]};
                a = MFMA(axh, Bih, a);
                a = MFMA(axl, Bih, a);
                a = MFMA(axh, Bil, a);
#pragma unroll
                for (int kt = 0; kt < 2; ++kt) {
                    const bf16x8 Bhh = *(const bf16x8*)(s + K1_HH_H + swz64(col, kt * 4 + q));
                    const bf16x8 Bhl = *(const bf16x8*)(s + K1_HH_L + swz64(col, kt * 4 + q));
                    a = MFMA(hfh[kt], Bhh, a);
                    a = MFMA(hfl[kt], Bhh, a);
                    a = MFMA(hfh[kt], Bhl, a);
                }
                C[g] = a;
            }
#pragma unroll
            for (int r = 0; r < 4; ++r) {
                float h = gate_act(C[0][r], C[1][r], C[2][r], C[3][r], cst[nt][r]);
                if (q < 2) {
                    u16 hh_, hl_; split2(h, hh_, hl_);
                    hb[(q * 4 + r) * 72 + ((nt * 16 + l15) ^ (r << 3))] = ((u32)hh_ << 16) | hl_;
                }
            }
        }
        // transpose-readback (wave-private LDS) + r1 store (real rows only)
#pragma unroll
        for (int kt = 0; kt < 2; ++kt) {
            u32 w[8];
            const int cb = (kt * 32 + q * 8) ^ ((l15 & 3) << 3);
            *(u32x4*)&w[0] = *(const u32x4*)&hb[(l15 & 7) * 72 + cb];
            *(u32x4*)&w[4] = *(const u32x4*)&hb[(l15 & 7) * 72 + cb + 4];
            u32 dh[4], dl[4];
#pragma unroll
            for (int p = 0; p < 4; ++p) {
                dh[p] = (w[p*2] >> 16) | (w[p*2+1] & 0xffff0000u);
                dl[p] = (w[p*2] & 0xffffu) | (w[p*2+1] << 16);
            }
            __builtin_memcpy(&hfh[kt], dh, 16);
            __builtin_memcpy(&hfl[kt], dl, 16);
            if (l15 < 8) {
                const size_t ro = ((size_t)lev * ch_rows + lloc) * 64 + kt * 32 + q * 8;
                *(u32x4*)(r1h + ro) = *(const u32x4*)dh;
                *(u32x4*)(r1l + ro) = *(const u32x4*)dl;
            }
        }
    }
}

// ============ Kernel 2: LSTM2 forward + fused heads ============
#define K2_IH_H 0
#define K2_IH_L 32768
#define K2_HH_H 65536
#define K2_HH_L 98304
#define K2_HD_H 131072
#define K2_HD_L 135168
#define K2_HB   139264
__global__ __launch_bounds__(512, 1)
void lstm2_kern(const float* __restrict__ in_aux,
                const float* __restrict__ Wtoa1, const float* __restrict__ btoa1,
                const float* __restrict__ Wtoa2, const float* __restrict__ btoa2,
                const float* __restrict__ wsf, const u16* __restrict__ wpk,
                const u16* __restrict__ r1h, const u16* __restrict__ r1l,
                int b_off, int ch_rows, float* __restrict__ out)
{
    __shared__ __align__(16) char s[157696];
    const int tid = threadIdx.x;
    for (int i = tid; i < 2048; i += 512) {
        int c = i >> 3, qk = i & 7;
        *(u32x4*)(s + K2_IH_H + swz64(c, qk)) = *(const u32x4*)(wpk + W2IH_HI + c * 64 + qk * 8);
        *(u32x4*)(s + K2_IH_L + swz64(c, qk)) = *(const u32x4*)(wpk + W2IH_LO + c * 64 + qk * 8);
        *(u32x4*)(s + K2_HH_H + swz64(c, qk)) = *(const u32x4*)(wpk + W2HH_HI + c * 64 + qk * 8);
        *(u32x4*)(s + K2_HH_L + swz64(c, qk)) = *(const u32x4*)(wpk + W2HH_LO + c * 64 + qk * 8);
    }
    for (int i = tid; i < 256; i += 512) {
        int c = i >> 3, qk = i & 7;
        *(u32x4*)(s + K2_HD_H + swz64(c, qk)) = *(const u32x4*)(wpk + WHD_HI + c * 64 + qk * 8);
        *(u32x4*)(s + K2_HD_L + swz64(c, qk)) = *(const u32x4*)(wpk + WHD_LO + c * 64 + qk * 8);
    }
    __syncthreads();   // the ONLY barrier

    const int lane = tid & 63, wv = tid >> 6;
    const int q = lane >> 4, l15 = lane & 15;
    const int lloc = blockIdx.x * 64 + wv * 8 + (l15 & 7);
    const int aRow = b_off + lloc;
    const int crow = b_off + blockIdx.x * 64 + wv * 8 + q * 4;
    u32* hb = (u32*)(s + K2_HB) + wv * 576;

    bf16x8 hfh[2], hfl[2];
    float cst[4][4];
    float b2r[4][4], bhd[2];
#pragma unroll
    for (int g = 0; g < 4; ++g)
#pragma unroll
        for (int nt = 0; nt < 4; ++nt)
            b2r[g][nt] = wsf[256 + g * 64 + nt * 16 + l15];
    bhd[0] = wsf[512 + l15];
    bhd[1] = wsf[528 + l15];

    // init h2_0 / c2_0
    {
        const float toa = in_aux[(size_t)aRow * 3 + 1];
#pragma unroll
        for (int kt = 0; kt < 2; ++kt) {
            u32 dh[4], dl[4];
#pragma unroll
            for (int p = 0; p < 4; ++p) {
                int k0 = kt * 32 + q * 8 + p * 2;
                float ha = fmaf(toa, Wtoa2[k0],     btoa2[k0]);
                float hbv = fmaf(toa, Wtoa2[k0 + 1], btoa2[k0 + 1]);
                u16 hah, hal, hbh, hbl; split2(ha, hah, hal); split2(hbv, hbh, hbl);
                dh[p] = ((u32)hbh << 16) | hah;
                dl[p] = ((u32)hbl << 16) | hal;
            }
            __builtin_memcpy(&hfh[kt], dh, 16);
            __builtin_memcpy(&hfl[kt], dl, 16);
        }
#pragma unroll
        for (int r = 0; r < 4; ++r) {
            int cr = crow + r; if (cr > BATCH - 1) cr = BATCH - 1;
            const float toc = in_aux[(size_t)cr * 3 + 1];
#pragma unroll
            for (int nt = 0; nt < 4; ++nt) {
                int u = nt * 16 + l15;
                cst[nt][r] = fmaf(toc, Wtoa1[u], btoa1[u]);
            }
        }
    }

    // prefetch r1 frags for lev 0
    bf16x8 pxh[2], pxl[2];
#pragma unroll
    for (int kt = 0; kt < 2; ++kt) {
        const size_t ro = ((size_t)0 * ch_rows + lloc) * 64 + kt * 32 + q * 8;
        pxh[kt] = *(const bf16x8*)(r1h + ro);
        pxl[kt] = *(const bf16x8*)(r1l + ro);
    }

#pragma unroll 1
    for (int lev = 0; lev < NLEVS; ++lev) {
        bf16x8 axh[2], axl[2];
        axh[0] = pxh[0]; axh[1] = pxh[1];
        axl[0] = pxl[0]; axl[1] = pxl[1];
        if (lev < 59) {
#pragma unroll
            for (int kt = 0; kt < 2; ++kt) {
                const size_t ro = ((size_t)(lev + 1) * ch_rows + lloc) * 64 + kt * 32 + q * 8;
                pxh[kt] = *(const bf16x8*)(r1h + ro);
                pxl[kt] = *(const bf16x8*)(r1l + ro);
            }
        }
#pragma unroll
        for (int nt = 0; nt < 4; ++nt) {
            f32x4 C[4];
#pragma unroll
            for (int g = 0; g < 4; ++g) {
                const int col = g * 64 + nt * 16 + l15;
                f32x4 a = {b2r[g][nt], b2r[g][nt], b2r[g][nt], b2r[g][nt]};
#pragma unroll
                for (int kt = 0; kt < 2; ++kt) {
                    const bf16x8 Bih = *(const bf16x8*)(s + K2_IH_H + swz64(col, kt * 4 + q));
                    const bf16x8 Bil = *(const bf16x8*)(s + K2_IH_L + swz64(col, kt * 4 + q));
                    const bf16x8 Bhh = *(const bf16x8*)(s + K2_HH_H + swz64(col, kt * 4 + q));
                    const bf16x8 Bhl = *(const bf16x8*)(s + K2_HH_L + swz64(col, kt * 4 + q));
                    a = MFMA(axh[kt], Bih, a);
                    a = MFMA(axl[kt], Bih, a);
                    a = MFMA(axh[kt], Bil, a);
                    a = MFMA(hfh[kt], Bhh, a);
                    a = MFMA(hfl[kt], Bhh, a);
                    a = MFMA(hfh[kt], Bhl, a);
                }
                C[g] = a;
            }
#pragma unroll
            for (int r = 0; r < 4; ++r) {
                float h = gate_act(C[0][r], C[1][r], C[2][r], C[3][r], cst[nt][r]);
                if (q < 2) {
                    u16 hh_, hl_; split2(h, hh_, hl_);
                    hb[(q * 4 + r) * 72 + ((nt * 16 + l15) ^ (r << 3))] = ((u32)hh_ << 16) | hl_;
                }
            }
        }
        // transpose-readback
#pragma unroll
        for (int kt = 0; kt < 2; ++kt) {
            u32 w[8];
            const int cb = (kt * 32 + q * 8) ^ ((l15 & 3) << 3);
            *(u32x4*)&w[0] = *(const u32x4*)&hb[(l15 & 7) * 72 + cb];
            *(u32x4*)&w[4] = *(const u32x4*)&hb[(l15 & 7) * 72 + cb + 4];
            u32 dh[4], dl[4];
#pragma unroll
            for (int p = 0; p < 4; ++p) {
                dh[p] = (w[p*2] >> 16) | (w[p*2+1] & 0xffff0000u);
                dl[p] = (w[p*2] & 0xffffu) | (w[p*2+1] << 16);
            }
            __builtin_memcpy(&hfh[kt], dh, 16);
            __builtin_memcpy(&hfl[kt], dl, 16);
        }
        // heads on current h2
#pragma unroll
        for (int hnt = 0; hnt < 2; ++hnt) {
            const int col = hnt * 16 + l15;
            f32x4 a = {bhd[hnt], bhd[hnt], bhd[hnt], bhd[hnt]};
#pragma unroll
            for (int kt = 0; kt < 2; ++kt) {
                const bf16x8 Bh = *(const bf16x8*)(s + K2_HD_H + swz64(col, kt * 4 + q));
                const bf16x8 Bl = *(const bf16x8*)(s + K2_HD_L + swz64(col, kt * 4 + q));
                a = MFMA(hfh[kt], Bh, a);
                a = MFMA(hfl[kt], Bh, a);
                a = MFMA(hfh[kt], Bl, a);
            }
            if (q < 2) {
#pragma unroll
                for (int r = 0; r < 4; ++r) {
                    const size_t gb = (size_t)(crow + r);
                    if (hnt == 0) {
                        out[MEM_OFF + (gb * NLEVS + lev) * 16 + l15] = tanh_(a[r]);
                    } else {
                        if (l15 < 4) out[(gb * NLEVS + lev) * 4 + l15] = a[r];
                        else if (l15 < 7 && lev == 59) out[SFC_OFF + gb * 3 + (l15 - 4)] = a[r];
                    }
                }
            }
        }
    }
}

extern "C" void kernel_launch(void* const* d_in, const int* in_sizes, int n_in,
                              void* d_out, int out_size, void* d_ws, size_t ws_size,
                              hipStream_t stream) {
    const float* in_main = (const float*)d_in[0];
    const float* in_aux  = (const float*)d_in[1];
    const float* in_mem  = (const float*)d_in[2];
    const float* Wsfc1   = (const float*)d_in[3];
    const float* bsfc1   = (const float*)d_in[4];
    const float* Wsfc2   = (const float*)d_in[5];
    const float* bsfc2   = (const float*)d_in[6];
    const float* Wtoa1   = (const float*)d_in[7];
    const float* btoa1   = (const float*)d_in[8];
    const float* Wtoa2   = (const float*)d_in[9];
    const float* btoa2   = (const float*)d_in[10];
    const float* W1ih    = (const float*)d_in[11];
    const float* W1hh    = (const float*)d_in[12];
    const float* b1ih    = (const float*)d_in[13];
    const float* b1hh    = (const float*)d_in[14];
    const float* W2ih    = (const float*)d_in[15];
    const float* W2hh    = (const float*)d_in[16];
    const float* b2ih    = (const float*)d_in[17];
    const float* b2hh    = (const float*)d_in[18];
    const float* Wlat    = (const float*)d_in[19];
    const float* blat    = (const float*)d_in[20];
    const float* Wout    = (const float*)d_in[21];
    const float* bout    = (const float*)d_in[22];
    const float* Wsfco   = (const float*)d_in[23];
    const float* bsfco   = (const float*)d_in[24];
    float* out           = (float*)d_out;

    float* wsf    = (float*)d_ws;
    u16*   wpk    = (u16*)((char*)d_ws + WPK_BYTE_OFF);
    u16*   r1base = (u16*)((char*)d_ws + WS_R1_BYTE_OFF);

    setup_pack<<<235, 256, 0, stream>>>(W1ih, W1hh, W2ih, W2hh, Wlat, Wout, Wsfco,
                                        b1ih, b1hh, b2ih, b2hh, blat, bout, bsfco,
                                        wsf, wpk);

    const size_t avail = (ws_size > WS_R1_BYTE_OFF) ? ws_size - WS_R1_BYTE_OFF : 0;
    const size_t per_row = (size_t)NLEVS * 64 * 2 * 2;   // hi+lo u16 planes = 15360 B/row
    size_t rows = avail / per_row;
    rows &= ~(size_t)63;
    if (rows > BATCH) rows = BATCH;
    if (rows < 64) rows = 64;

    for (int off = 0; off < BATCH; off += (int)rows) {
        int nr = (BATCH - off < (int)rows) ? (BATCH - off) : (int)rows;
        u16* r1h = r1base;
        u16* r1l = r1base + (size_t)NLEVS * nr * 64;
        lstm1_kern<<<nr / 64, 512, 0, stream>>>(
            in_main, in_aux, in_mem, Wsfc1, bsfc1, Wsfc2, bsfc2,
            wsf, wpk, r1h, r1l, off, nr);
        lstm2_kern<<<nr / 64, 512, 0, stream>>>(
            in_aux, Wtoa1, btoa1, Wtoa2, btoa2,
            wsf, wpk, r1h, r1l, off, nr, out);
    }
}

// Round 9
// 544.839 us; speedup vs baseline: 1.3692x; 1.3692x over previous
//
#include <hip/hip_runtime.h>
#include <hip/hip_bf16.h>

typedef unsigned short u16;
typedef unsigned int u32;
typedef __attribute__((ext_vector_type(8))) short bf16x8;
typedef __attribute__((ext_vector_type(4))) float f32x4;
typedef __attribute__((ext_vector_type(4))) u32 u32x4;

#define BATCH 16384
#define NLEVS 60

#define SFC_OFF ((size_t)BATCH * NLEVS * 4)
#define MEM_OFF (SFC_OFF + (size_t)BATCH * 3)

// packed u16 plane offsets (in u16 units, from wpk) — layout validated r5-r8
#define W1IH_HI 0
#define W1IH_LO 8192
#define W1HH_HI 16384
#define W1HH_LO 32768
#define W2IH_HI 49152
#define W2IH_LO 65536
#define W2HH_HI 81920
#define W2HH_LO 98304
#define WHD_HI  114688
#define WHD_LO  116736

#define WPK_BYTE_OFF 4096
#define WS_R1_BYTE_OFF 262144

// gate prescale: i,f,o by -log2(e) (sigmoid), g by +2*log2(e) (tanh)
#define SIGK -1.4426950408889634f
#define TANK  2.8853900817779268f

#define MFMA(a, b, c) __builtin_amdgcn_mfma_f32_16x16x32_bf16((a), (b), (c), 0, 0, 0)

__device__ __forceinline__ float bf2f(u16 u) {
    union { u32 i; float f; } v; v.i = (u32)u << 16; return v.f;
}
__device__ __forceinline__ u16 f2bf(float f) {
    __hip_bfloat16 b = __float2bfloat16(f);
    u16 u; __builtin_memcpy(&u, &b, 2); return u;
}
__device__ __forceinline__ void split2(float w, u16& hi, u16& lo) {
    u16 h = f2bf(w);
    hi = h;
    lo = f2bf(w - bf2f(h));
}
__device__ __forceinline__ float tanh_(float x) {      // plain tanh (inits/heads)
    float ax = fabsf(x);
    float e  = __builtin_amdgcn_exp2f(-TANK * ax);
    float t  = (1.0f - e) * __builtin_amdgcn_rcpf(1.0f + e);
    return copysignf(t, x);
}

// Pack all weights to bf16 hi/lo planes with gate prescale; fuse biases and
// Wout@Wlat head (heads unscaled). Validated r5-r8.
__global__ void setup_pack(const float* __restrict__ W1ih, const float* __restrict__ W1hh,
                           const float* __restrict__ W2ih, const float* __restrict__ W2hh,
                           const float* __restrict__ Wlat, const float* __restrict__ Wout,
                           const float* __restrict__ Wsfco,
                           const float* __restrict__ b1ih, const float* __restrict__ b1hh,
                           const float* __restrict__ b2ih, const float* __restrict__ b2hh,
                           const float* __restrict__ blat, const float* __restrict__ bout,
                           const float* __restrict__ bsfco,
                           float* __restrict__ wsf, u16* __restrict__ wpk)
{
    int t = blockIdx.x * 256 + threadIdx.x;
    if (t < 256) {
        float sc = ((t >> 6) == 2) ? TANK : SIGK;
        wsf[t] = (b1ih[t] + b1hh[t]) * sc; return;
    }
    if (t < 512) {
        int j = t - 256;
        float sc = ((j >> 6) == 2) ? TANK : SIGK;
        wsf[256 + j] = (b2ih[j] + b2hh[j]) * sc; return;
    }
    if (t < 544) {
        int j = t - 512; float v;
        if (j < 16) v = blat[j];
        else if (j < 20) { v = bout[j - 16]; for (int m = 0; m < 16; ++m) v += Wout[(j - 16) * 16 + m] * blat[m]; }
        else if (j < 23) v = bsfco[j - 20];
        else v = 0.f;
        wsf[512 + j] = v; return;
    }
    int u = t - 544;
    float w; int hi_off, lo_off, idx, gate = -1;
    if (u < 8192) {
        int col = u >> 5, k = u & 31;
        w = (k < 20) ? W1ih[col * 20 + k] : 0.f;
        hi_off = W1IH_HI; lo_off = W1IH_LO; idx = u; gate = col >> 6;
    } else if (u < 24576) {
        idx = u - 8192; w = W1hh[idx]; hi_off = W1HH_HI; lo_off = W1HH_LO; gate = idx >> 12;
    } else if (u < 40960) {
        idx = u - 24576; w = W2ih[idx]; hi_off = W2IH_HI; lo_off = W2IH_LO; gate = idx >> 12;
    } else if (u < 57344) {
        idx = u - 40960; w = W2hh[idx]; hi_off = W2HH_HI; lo_off = W2HH_LO; gate = idx >> 12;
    } else if (u < 59392) {
        idx = u - 57344; int hc = idx >> 6, k = idx & 63;
        if (hc < 16) w = Wlat[hc * 64 + k];
        else if (hc < 20) { w = 0.f; for (int m = 0; m < 16; ++m) w += Wout[(hc - 16) * 16 + m] * Wlat[m * 64 + k]; }
        else if (hc < 23) w = Wsfco[(hc - 20) * 64 + k];
        else w = 0.f;
        hi_off = WHD_HI; lo_off = WHD_LO;
    } else return;
    if (gate >= 0) w *= (gate == 2) ? TANK : SIGK;
    u16 h_, l_; split2(w, h_, l_);
    wpk[hi_off + idx] = h_;
    wpk[lo_off + idx] = l_;
}

// Fused gate epilogue (prescaled pre-activations). Validated r8.
__device__ __forceinline__ float gate_act(float si, float sf, float sg, float so, float& c) {
    float ei = __builtin_amdgcn_exp2f(si);
    float ef = __builtin_amdgcn_exp2f(sf);
    float eo = __builtin_amdgcn_exp2f(so);
    float eg = __builtin_amdgcn_exp2f(-fabsf(sg));
    float p2 = copysignf(1.f - eg, sg) * __builtin_amdgcn_rcpf((1.f + ei) * (1.f + eg));
    c = fmaf(__builtin_amdgcn_rcpf(1.f + ef), c, p2);
    float ec = __builtin_amdgcn_exp2f(-fabsf(TANK * c));
    return copysignf(1.f - ec, c) * __builtin_amdgcn_rcpf((1.f + eo) * (1.f + ec));
}

// ============ Kernel 1: LSTM1 (reversed levels), column-split ============
// 256 thr = 4 waves; block owns 16 batch rows; wave wv owns units [wv*16,wv*16+16)
// for ALL 4 gates, weights resident in VGPRs. h exchanged per step via small
// double-buffered LDS (one barrier per step).
__global__ __launch_bounds__(256, 2)
void lstm1_kern(const float* __restrict__ in_main, const float* __restrict__ in_aux,
                const float* __restrict__ in_mem,
                const float* __restrict__ Wsfc1, const float* __restrict__ bsfc1,
                const float* __restrict__ Wsfc2, const float* __restrict__ bsfc2,
                const float* __restrict__ wsf, const u16* __restrict__ wpk,
                u16* __restrict__ r1h, u16* __restrict__ r1l,
                int b_off, int ch_rows)
{
    __shared__ __align__(16) u32 hbuf[2][16][68];   // packed (hi<<16|lo)
    const int tid = threadIdx.x;
    const int lane = tid & 63, wv = tid >> 6;
    const int q = lane >> 4, l15 = lane & 15;
    const int lloc = blockIdx.x * 16 + l15;      // this lane's A-row (chunk-local)
    const int aRow = b_off + lloc;
    const int crow = b_off + blockIdx.x * 16 + q * 4;   // C-row base
    const int unit = wv * 16 + l15;              // this lane's unit (C col)

    // ---- resident B-frags: 4 gate-coltiles for this wave's unit group
    bf16x8 Bih_h[4], Bih_l[4], Bhh_h[4][2], Bhh_l[4][2];
    float bias[4];
#pragma unroll
    for (int g = 0; g < 4; ++g) {
        const int col = g * 64 + unit;
        Bih_h[g] = *(const bf16x8*)(wpk + W1IH_HI + col * 32 + q * 8);
        Bih_l[g] = *(const bf16x8*)(wpk + W1IH_LO + col * 32 + q * 8);
#pragma unroll
        for (int kt = 0; kt < 2; ++kt) {
            Bhh_h[g][kt] = *(const bf16x8*)(wpk + W1HH_HI + col * 64 + kt * 32 + q * 8);
            Bhh_l[g][kt] = *(const bf16x8*)(wpk + W1HH_LO + col * 64 + kt * 32 + q * 8);
        }
        bias[g] = wsf[col];
    }

    bf16x8 hfh[2], hfl[2];
    float cst[4];

    // ---- init h0 (A-frag, row l15) and c0 (C-layout, rows crow+r, unit)
    {
        const float a0 = in_aux[(size_t)aRow * 3];
        const float a1 = in_aux[(size_t)aRow * 3 + 1];
        const float a2 = in_aux[(size_t)aRow * 3 + 2];
#pragma unroll
        for (int kt = 0; kt < 2; ++kt) {
            u32 dh[4], dl[4];
#pragma unroll
            for (int p = 0; p < 4; ++p) {
                int k0 = kt * 32 + q * 8 + p * 2;
                float ha = tanh_(fmaf(a0, Wsfc1[k0*3], fmaf(a1, Wsfc1[k0*3+1], fmaf(a2, Wsfc1[k0*3+2], bsfc1[k0]))));
                float hbv = tanh_(fmaf(a0, Wsfc1[k0*3+3], fmaf(a1, Wsfc1[k0*3+4], fmaf(a2, Wsfc1[k0*3+5], bsfc1[k0+1]))));
                u16 hah, hal, hbh, hbl; split2(ha, hah, hal); split2(hbv, hbh, hbl);
                dh[p] = ((u32)hbh << 16) | hah;
                dl[p] = ((u32)hbl << 16) | hal;
            }
            __builtin_memcpy(&hfh[kt], dh, 16);
            __builtin_memcpy(&hfl[kt], dl, 16);
        }
#pragma unroll
        for (int r = 0; r < 4; ++r) {
            const size_t gr = (size_t)(crow + r) * 3;
            float c0 = in_aux[gr], c1 = in_aux[gr + 1], c2 = in_aux[gr + 2];
            cst[r] = tanh_(fmaf(c0, Wsfc2[unit*3], fmaf(c1, Wsfc2[unit*3+1], fmaf(c2, Wsfc2[unit*3+2], bsfc2[unit]))));
        }
    }

    // ---- x prefetch (lev 59); per-q float4 slices of [main(4) | mem(16)]
    float4 XA = {0,0,0,0}, XB = {0,0,0,0};
    {
        const size_t mi = (size_t)aRow * NLEVS + 59;
        if (q == 0)      { XA = *(const float4*)(in_main + mi * 4);      XB = *(const float4*)(in_mem + mi * 16); }
        else if (q == 1) { XA = *(const float4*)(in_mem + mi * 16 + 4);  XB = *(const float4*)(in_mem + mi * 16 + 8); }
        else if (q == 2) { XA = *(const float4*)(in_mem + mi * 16 + 12); }
    }

#pragma unroll 1
    for (int t = 0; t < NLEVS; ++t) {
        const int lev = 59 - t;
        const int buf = t & 1;
        // build x A-frag (K=32, k>=20 zero-padded to match zeroed W rows)
        bf16x8 axh, axl;
        {
            float xv[8] = {0, 0, 0, 0, 0, 0, 0, 0};
            if (q < 2)       { xv[0]=XA.x; xv[1]=XA.y; xv[2]=XA.z; xv[3]=XA.w; xv[4]=XB.x; xv[5]=XB.y; xv[6]=XB.z; xv[7]=XB.w; }
            else if (q == 2) { xv[0]=XA.x; xv[1]=XA.y; xv[2]=XA.z; xv[3]=XA.w; }
            u32 dh[4], dl[4];
#pragma unroll
            for (int p = 0; p < 4; ++p) {
                u16 h0, l0, h1, l1; split2(xv[p*2], h0, l0); split2(xv[p*2+1], h1, l1);
                dh[p] = ((u32)h1 << 16) | h0;
                dl[p] = ((u32)l1 << 16) | l0;
            }
            __builtin_memcpy(&axh, dh, 16);
            __builtin_memcpy(&axl, dl, 16);
        }
        if (t < 59) {
            const size_t mi = (size_t)aRow * NLEVS + (lev - 1);
            if (q == 0)      { XA = *(const float4*)(in_main + mi * 4);      XB = *(const float4*)(in_mem + mi * 16); }
            else if (q == 1) { XA = *(const float4*)(in_mem + mi * 16 + 4);  XB = *(const float4*)(in_mem + mi * 16 + 8); }
            else if (q == 2) { XA = *(const float4*)(in_mem + mi * 16 + 12); }
        }
        // gates for own 16 units (all 4 gates)
        f32x4 C[4];
#pragma unroll
        for (int g = 0; g < 4; ++g) {
            f32x4 a = {bias[g], bias[g], bias[g], bias[g]};
            a = MFMA(axh, Bih_h[g], a);
            a = MFMA(axl, Bih_h[g], a);
            a = MFMA(axh, Bih_l[g], a);
#pragma unroll
            for (int kt = 0; kt < 2; ++kt) {
                a = MFMA(hfh[kt], Bhh_h[g][kt], a);
                a = MFMA(hfl[kt], Bhh_h[g][kt], a);
                a = MFMA(hfh[kt], Bhh_l[g][kt], a);
            }
            C[g] = a;
        }
#pragma unroll
        for (int r = 0; r < 4; ++r) {
            float h = gate_act(C[0][r], C[1][r], C[2][r], C[3][r], cst[r]);
            u16 hh_, hl_; split2(h, hh_, hl_);
            hbuf[buf][q * 4 + r][unit] = ((u32)hh_ << 16) | hl_;
        }
        __syncthreads();   // one barrier/step; double buffer makes overwrites safe
        // read full h as A-frags + store r1 planes
#pragma unroll
        for (int kt = 0; kt < 2; ++kt) {
            const int k0 = kt * 32 + q * 8;
            u32 w[8];
            *(u32x4*)&w[0] = *(const u32x4*)&hbuf[buf][l15][k0];
            *(u32x4*)&w[4] = *(const u32x4*)&hbuf[buf][l15][k0 + 4];
            u32 dh[4], dl[4];
#pragma unroll
            for (int p = 0; p < 4; ++p) {
                dh[p] = (w[p*2] >> 16) | (w[p*2+1] & 0xffff0000u);
                dl[p] = (w[p*2] & 0xffffu) | (w[p*2+1] << 16);
            }
            __builtin_memcpy(&hfh[kt], dh, 16);
            __builtin_memcpy(&hfl[kt], dl, 16);
            const size_t ro = ((size_t)lev * ch_rows + lloc) * 64 + k0;
            *(u32x4*)(r1h + ro) = *(const u32x4*)dh;
            *(u32x4*)(r1l + ro) = *(const u32x4*)dl;
        }
    }
}

// ============ Kernel 2: LSTM2 forward + fused heads, column-split ============
__global__ __launch_bounds__(256, 2)
void lstm2_kern(const float* __restrict__ in_aux,
                const float* __restrict__ Wtoa1, const float* __restrict__ btoa1,
                const float* __restrict__ Wtoa2, const float* __restrict__ btoa2,
                const float* __restrict__ wsf, const u16* __restrict__ wpk,
                const u16* __restrict__ r1h, const u16* __restrict__ r1l,
                int b_off, int ch_rows, float* __restrict__ out)
{
    __shared__ __align__(16) u32 hbuf[2][16][68];
    const int tid = threadIdx.x;
    const int lane = tid & 63, wv = tid >> 6;
    const int q = lane >> 4, l15 = lane & 15;
    const int lloc = blockIdx.x * 16 + l15;
    const int aRow = b_off + lloc;
    const int crow = b_off + blockIdx.x * 16 + q * 4;
    const int unit = wv * 16 + l15;

    // resident B-frags (K=64 both matrices)
    bf16x8 Bih_h[4][2], Bih_l[4][2], Bhh_h[4][2], Bhh_l[4][2];
    float bias[4];
#pragma unroll
    for (int g = 0; g < 4; ++g) {
        const int col = g * 64 + unit;
#pragma unroll
        for (int kt = 0; kt < 2; ++kt) {
            Bih_h[g][kt] = *(const bf16x8*)(wpk + W2IH_HI + col * 64 + kt * 32 + q * 8);
            Bih_l[g][kt] = *(const bf16x8*)(wpk + W2IH_LO + col * 64 + kt * 32 + q * 8);
            Bhh_h[g][kt] = *(const bf16x8*)(wpk + W2HH_HI + col * 64 + kt * 32 + q * 8);
            Bhh_l[g][kt] = *(const bf16x8*)(wpk + W2HH_LO + col * 64 + kt * 32 + q * 8);
        }
        bias[g] = wsf[256 + col];
    }
    // head frags on waves 2,3 (coltile wv-2: cols 0-15 = Wlat/mem, 16-31 = out+sfc)
    bf16x8 Bhd_h[2], Bhd_l[2];
    float bhd = 0.f;
    if (wv >= 2) {
        const int hc = (wv - 2) * 16 + l15;
#pragma unroll
        for (int kt = 0; kt < 2; ++kt) {
            Bhd_h[kt] = *(const bf16x8*)(wpk + WHD_HI + hc * 64 + kt * 32 + q * 8);
            Bhd_l[kt] = *(const bf16x8*)(wpk + WHD_LO + hc * 64 + kt * 32 + q * 8);
        }
        bhd = wsf[512 + hc];
    }

    bf16x8 hfh[2], hfl[2];
    float cst[4];

    // init h2_0 (A-frag) / c2_0 (C-layout)
    {
        const float toa = in_aux[(size_t)aRow * 3 + 1];
#pragma unroll
        for (int kt = 0; kt < 2; ++kt) {
            u32 dh[4], dl[4];
#pragma unroll
            for (int p = 0; p < 4; ++p) {
                int k0 = kt * 32 + q * 8 + p * 2;
                float ha  = fmaf(toa, Wtoa2[k0],     btoa2[k0]);
                float hbv = fmaf(toa, Wtoa2[k0 + 1], btoa2[k0 + 1]);
                u16 hah, hal, hbh, hbl; split2(ha, hah, hal); split2(hbv, hbh, hbl);
                dh[p] = ((u32)hbh << 16) | hah;
                dl[p] = ((u32)hbl << 16) | hal;
            }
            __builtin_memcpy(&hfh[kt], dh, 16);
            __builtin_memcpy(&hfl[kt], dl, 16);
        }
#pragma unroll
        for (int r = 0; r < 4; ++r) {
            const float toc = in_aux[(size_t)(crow + r) * 3 + 1];
            cst[r] = fmaf(toc, Wtoa1[unit], btoa1[unit]);
        }
    }

    // prefetch x2 (lev 0) from r1 planes (already A-frag layout)
    bf16x8 pxh[2], pxl[2];
#pragma unroll
    for (int kt = 0; kt < 2; ++kt) {
        const size_t ro = ((size_t)0 * ch_rows + lloc) * 64 + kt * 32 + q * 8;
        pxh[kt] = *(const bf16x8*)(r1h + ro);
        pxl[kt] = *(const bf16x8*)(r1l + ro);
    }

#pragma unroll 1
    for (int lev = 0; lev < NLEVS; ++lev) {
        const int buf = lev & 1;
        bf16x8 axh[2], axl[2];
        axh[0] = pxh[0]; axh[1] = pxh[1];
        axl[0] = pxl[0]; axl[1] = pxl[1];
        if (lev < 59) {
#pragma unroll
            for (int kt = 0; kt < 2; ++kt) {
                const size_t ro = ((size_t)(lev + 1) * ch_rows + lloc) * 64 + kt * 32 + q * 8;
                pxh[kt] = *(const bf16x8*)(r1h + ro);
                pxl[kt] = *(const bf16x8*)(r1l + ro);
            }
        }
        f32x4 C[4];
#pragma unroll
        for (int g = 0; g < 4; ++g) {
            f32x4 a = {bias[g], bias[g], bias[g], bias[g]};
#pragma unroll
            for (int kt = 0; kt < 2; ++kt) {
                a = MFMA(axh[kt], Bih_h[g][kt], a);
                a = MFMA(axl[kt], Bih_h[g][kt], a);
                a = MFMA(axh[kt], Bih_l[g][kt], a);
                a = MFMA(hfh[kt], Bhh_h[g][kt], a);
                a = MFMA(hfl[kt], Bhh_h[g][kt], a);
                a = MFMA(hfh[kt], Bhh_l[g][kt], a);
            }
            C[g] = a;
        }
#pragma unroll
        for (int r = 0; r < 4; ++r) {
            float h = gate_act(C[0][r], C[1][r], C[2][r], C[3][r], cst[r]);
            u16 hh_, hl_; split2(h, hh_, hl_);
            hbuf[buf][q * 4 + r][unit] = ((u32)hh_ << 16) | hl_;
        }
        __syncthreads();
        // read full h2 as A-frags
#pragma unroll
        for (int kt = 0; kt < 2; ++kt) {
            const int k0 = kt * 32 + q * 8;
            u32 w[8];
            *(u32x4*)&w[0] = *(const u32x4*)&hbuf[buf][l15][k0];
            *(u32x4*)&w[4] = *(const u32x4*)&hbuf[buf][l15][k0 + 4];
            u32 dh[4], dl[4];
#pragma unroll
            for (int p = 0; p < 4; ++p) {
                dh[p] = (w[p*2] >> 16) | (w[p*2+1] & 0xffff0000u);
                dl[p] = (w[p*2] & 0xffffu) | (w[p*2+1] << 16);
            }
            __builtin_memcpy(&hfh[kt], dh, 16);
            __builtin_memcpy(&hfl[kt], dl, 16);
        }
        // heads on fresh h2 (waves 2,3 only): 6 MFMA + writes
        if (wv >= 2) {
            f32x4 a = {bhd, bhd, bhd, bhd};
#pragma unroll
            for (int kt = 0; kt < 2; ++kt) {
                a = MFMA(hfh[kt], Bhd_h[kt], a);
                a = MFMA(hfl[kt], Bhd_h[kt], a);
                a = MFMA(hfh[kt], Bhd_l[kt], a);
            }
#pragma unroll
            for (int r = 0; r < 4; ++r) {
                const size_t gb = (size_t)(crow + r);
                if (wv == 2) {
                    out[MEM_OFF + (gb * NLEVS + lev) * 16 + l15] = tanh_(a[r]);
                } else {
                    if (l15 < 4) out[(gb * NLEVS + lev) * 4 + l15] = a[r];
                    else if (l15 < 7 && lev == 59) out[SFC_OFF + gb * 3 + (l15 - 4)] = a[r];
                }
            }
        }
    }
}

extern "C" void kernel_launch(void* const* d_in, const int* in_sizes, int n_in,
                              void* d_out, int out_size, void* d_ws, size_t ws_size,
                              hipStream_t stream) {
    const float* in_main = (const float*)d_in[0];
    const float* in_aux  = (const float*)d_in[1];
    const float* in_mem  = (const float*)d_in[2];
    const float* Wsfc1   = (const float*)d_in[3];
    const float* bsfc1   = (const float*)d_in[4];
    const float* Wsfc2   = (const float*)d_in[5];
    const float* bsfc2   = (const float*)d_in[6];
    const float* Wtoa1   = (const float*)d_in[7];
    const float* btoa1   = (const float*)d_in[8];
    const float* Wtoa2   = (const float*)d_in[9];
    const float* btoa2   = (const float*)d_in[10];
    const float* W1ih    = (const float*)d_in[11];
    const float* W1hh    = (const float*)d_in[12];
    const float* b1ih    = (const float*)d_in[13];
    const float* b1hh    = (const float*)d_in[14];
    const float* W2ih    = (const float*)d_in[15];
    const float* W2hh    = (const float*)d_in[16];
    const float* b2ih    = (const float*)d_in[17];
    const float* b2hh    = (const float*)d_in[18];
    const float* Wlat    = (const float*)d_in[19];
    const float* blat    = (const float*)d_in[20];
    const float* Wout    = (const float*)d_in[21];
    const float* bout    = (const float*)d_in[22];
    const float* Wsfco   = (const float*)d_in[23];
    const float* bsfco   = (const float*)d_in[24];
    float* out           = (float*)d_out;

    float* wsf    = (float*)d_ws;
    u16*   wpk    = (u16*)((char*)d_ws + WPK_BYTE_OFF);
    u16*   r1base = (u16*)((char*)d_ws + WS_R1_BYTE_OFF);

    setup_pack<<<235, 256, 0, stream>>>(W1ih, W1hh, W2ih, W2hh, Wlat, Wout, Wsfco,
                                        b1ih, b1hh, b2ih, b2hh, blat, bout, bsfco,
                                        wsf, wpk);

    const size_t avail = (ws_size > WS_R1_BYTE_OFF) ? ws_size - WS_R1_BYTE_OFF : 0;
    const size_t per_row = (size_t)NLEVS * 64 * 2 * 2;   // hi+lo u16 planes = 15360 B/row
    size_t rows = avail / per_row;
    rows &= ~(size_t)15;
    if (rows > BATCH) rows = BATCH;
    if (rows < 16) rows = 16;

    for (int off = 0; off < BATCH; off += (int)rows) {
        int nr = (BATCH - off < (int)rows) ? (BATCH - off) : (int)rows;
        u16* r1h = r1base;
        u16* r1l = r1base + (size_t)NLEVS * nr * 64;
        lstm1_kern<<<nr / 16, 256, 0, stream>>>(
            in_main, in_aux, in_mem, Wsfc1, bsfc1, Wsfc2, bsfc2,
            wsf, wpk, r1h, r1l, off, nr);
        lstm2_kern<<<nr / 16, 256, 0, stream>>>(
            in_aux, Wtoa1, btoa1, Wtoa2, btoa2,
            wsf, wpk, r1h, r1l, off, nr, out);
    }
}

// Round 11
// 488.757 us; speedup vs baseline: 1.5263x; 1.1147x over previous
//
#include <hip/hip_runtime.h>
#include <hip/hip_bf16.h>

typedef unsigned short u16;
typedef unsigned int u32;
typedef __attribute__((ext_vector_type(8))) short bf16x8;
typedef __attribute__((ext_vector_type(4))) float f32x4;
typedef __attribute__((ext_vector_type(4))) u32 u32x4;

#define BATCH 16384
#define NLEVS 60

#define SFC_OFF ((size_t)BATCH * NLEVS * 4)
#define MEM_OFF (SFC_OFF + (size_t)BATCH * 3)

// packed u16 plane offsets (in u16 units, from wpk) — layout validated r5-r10
#define W1IH_HI 0
#define W1IH_LO 8192
#define W1HH_HI 16384
#define W1HH_LO 32768
#define W2IH_HI 49152
#define W2IH_LO 65536
#define W2HH_HI 81920
#define W2HH_LO 98304
#define WHD_HI  114688
#define WHD_LO  116736

#define WPK_BYTE_OFF 4096
#define WS_R1_BYTE_OFF 262144

// gate prescale: i,f,o by -log2(e) (sigmoid), g by +2*log2(e) (tanh)
#define SIGK -1.4426950408889634f
#define TANK  2.8853900817779268f

#define MFMA(a, b, c) __builtin_amdgcn_mfma_f32_16x16x32_bf16((a), (b), (c), 0, 0, 0)

__device__ __forceinline__ float bf2f(u16 u) {
    union { u32 i; float f; } v; v.i = (u32)u << 16; return v.f;
}
__device__ __forceinline__ u16 f2bf(float f) {
    __hip_bfloat16 b = __float2bfloat16(f);
    u16 u; __builtin_memcpy(&u, &b, 2); return u;
}
__device__ __forceinline__ void split2(float w, u16& hi, u16& lo) {
    u16 h = f2bf(w);
    hi = h;
    lo = f2bf(w - bf2f(h));
}
__device__ __forceinline__ float tanh_(float x) {
    float ax = fabsf(x);
    float e  = __builtin_amdgcn_exp2f(-TANK * ax);
    float t  = (1.0f - e) * __builtin_amdgcn_rcpf(1.0f + e);
    return copysignf(t, x);
}

// Pack all weights to bf16 hi/lo planes with gate prescale; fuse biases and
// Wout@Wlat head (heads unscaled). Validated r5-r10.
__global__ void setup_pack(const float* __restrict__ W1ih, const float* __restrict__ W1hh,
                           const float* __restrict__ W2ih, const float* __restrict__ W2hh,
                           const float* __restrict__ Wlat, const float* __restrict__ Wout,
                           const float* __restrict__ Wsfco,
                           const float* __restrict__ b1ih, const float* __restrict__ b1hh,
                           const float* __restrict__ b2ih, const float* __restrict__ b2hh,
                           const float* __restrict__ blat, const float* __restrict__ bout,
                           const float* __restrict__ bsfco,
                           float* __restrict__ wsf, u16* __restrict__ wpk)
{
    int t = blockIdx.x * 256 + threadIdx.x;
    if (t < 256) {
        float sc = ((t >> 6) == 2) ? TANK : SIGK;
        wsf[t] = (b1ih[t] + b1hh[t]) * sc; return;
    }
    if (t < 512) {
        int j = t - 256;
        float sc = ((j >> 6) == 2) ? TANK : SIGK;
        wsf[256 + j] = (b2ih[j] + b2hh[j]) * sc; return;
    }
    if (t < 544) {
        int j = t - 512; float v;
        if (j < 16) v = blat[j];
        else if (j < 20) { v = bout[j - 16]; for (int m = 0; m < 16; ++m) v += Wout[(j - 16) * 16 + m] * blat[m]; }
        else if (j < 23) v = bsfco[j - 20];
        else v = 0.f;
        wsf[512 + j] = v; return;
    }
    int u = t - 544;
    float w; int hi_off, lo_off, idx, gate = -1;
    if (u < 8192) {
        int col = u >> 5, k = u & 31;
        w = (k < 20) ? W1ih[col * 20 + k] : 0.f;
        hi_off = W1IH_HI; lo_off = W1IH_LO; idx = u; gate = col >> 6;
    } else if (u < 24576) {
        idx = u - 8192; w = W1hh[idx]; hi_off = W1HH_HI; lo_off = W1HH_LO; gate = idx >> 12;
    } else if (u < 40960) {
        idx = u - 24576; w = W2ih[idx]; hi_off = W2IH_HI; lo_off = W2IH_LO; gate = idx >> 12;
    } else if (u < 57344) {
        idx = u - 40960; w = W2hh[idx]; hi_off = W2HH_HI; lo_off = W2HH_LO; gate = idx >> 12;
    } else if (u < 59392) {
        idx = u - 57344; int hc = idx >> 6, k = idx & 63;
        if (hc < 16) w = Wlat[hc * 64 + k];
        else if (hc < 20) { w = 0.f; for (int m = 0; m < 16; ++m) w += Wout[(hc - 16) * 16 + m] * Wlat[m * 64 + k]; }
        else if (hc < 23) w = Wsfco[(hc - 20) * 64 + k];
        else w = 0.f;
        hi_off = WHD_HI; lo_off = WHD_LO;
    } else return;
    if (gate >= 0) w *= (gate == 2) ? TANK : SIGK;
    u16 h_, l_; split2(w, h_, l_);
    wpk[hi_off + idx] = h_;
    wpk[lo_off + idx] = l_;
}

// Fused gate epilogue (prescaled pre-activations). Validated r8-r10.
__device__ __forceinline__ float gate_act(float si, float sf, float sg, float so, float& c) {
    float ei = __builtin_amdgcn_exp2f(si);
    float ef = __builtin_amdgcn_exp2f(sf);
    float eo = __builtin_amdgcn_exp2f(so);
    float eg = __builtin_amdgcn_exp2f(-fabsf(sg));
    float p2 = copysignf(1.f - eg, sg) * __builtin_amdgcn_rcpf((1.f + ei) * (1.f + eg));
    c = fmaf(__builtin_amdgcn_rcpf(1.f + ef), c, p2);
    float ec = __builtin_amdgcn_exp2f(-fabsf(TANK * c));
    return copysignf(1.f - ec, c) * __builtin_amdgcn_rcpf((1.f + eo) * (1.f + ec));
}

// h-plane scratch layout: frag planes p = kt*4+q in [0,8):
//   r[( (lev*8 + p)*ch_rows + lloc ) * 8]  — 8 u16 (16 B) per lane, coalesced.

// ============ Kernel 1: LSTM1 (reversed levels) ============
// 256 thr = 4 waves x 16 rows; wave owns 16 units x 4 gates. Weights hi/lo
// resident in VGPRs (~96); recurrent h hi/lo via two direct-fragment LDS
// planes (zero repack); x and r1 output single bf16.
__global__ __launch_bounds__(256, 2)
void lstm1_kern(const float* __restrict__ in_main, const float* __restrict__ in_aux,
                const float* __restrict__ in_mem,
                const float* __restrict__ Wsfc1, const float* __restrict__ bsfc1,
                const float* __restrict__ Wsfc2, const float* __restrict__ bsfc2,
                const float* __restrict__ wsf, const u16* __restrict__ wpk,
                u16* __restrict__ r1, int b_off, int ch_rows)
{
    __shared__ __align__(16) u16 hbh[2][16][72];
    __shared__ __align__(16) u16 hbl[2][16][72];
    const int tid = threadIdx.x;
    const int lane = tid & 63, wv = tid >> 6;
    const int q = lane >> 4, l15 = lane & 15;
    const int lloc = blockIdx.x * 16 + l15;
    const int aRow = b_off + lloc;
    const int crow = b_off + blockIdx.x * 16 + q * 4;
    const int unit = wv * 16 + l15;

    bf16x8 Bih_h[4], Bih_l[4], Bhh_h[4][2], Bhh_l[4][2];
    float bias[4];
#pragma unroll
    for (int g = 0; g < 4; ++g) {
        const int col = g * 64 + unit;
        Bih_h[g] = *(const bf16x8*)(wpk + W1IH_HI + col * 32 + q * 8);
        Bih_l[g] = *(const bf16x8*)(wpk + W1IH_LO + col * 32 + q * 8);
#pragma unroll
        for (int kt = 0; kt < 2; ++kt) {
            Bhh_h[g][kt] = *(const bf16x8*)(wpk + W1HH_HI + col * 64 + kt * 32 + q * 8);
            Bhh_l[g][kt] = *(const bf16x8*)(wpk + W1HH_LO + col * 64 + kt * 32 + q * 8);
        }
        bias[g] = wsf[col];
    }

    bf16x8 hfh[2], hfl[2];
    float cst[4];

    // init h0 (A-frag hi/lo) and c0 (C-layout)
    {
        const float a0 = in_aux[(size_t)aRow * 3];
        const float a1 = in_aux[(size_t)aRow * 3 + 1];
        const float a2 = in_aux[(size_t)aRow * 3 + 2];
#pragma unroll
        for (int kt = 0; kt < 2; ++kt) {
            u32 dh[4], dl[4];
#pragma unroll
            for (int p = 0; p < 4; ++p) {
                int k0 = kt * 32 + q * 8 + p * 2;
                float ha = tanh_(fmaf(a0, Wsfc1[k0*3], fmaf(a1, Wsfc1[k0*3+1], fmaf(a2, Wsfc1[k0*3+2], bsfc1[k0]))));
                float hb = tanh_(fmaf(a0, Wsfc1[k0*3+3], fmaf(a1, Wsfc1[k0*3+4], fmaf(a2, Wsfc1[k0*3+5], bsfc1[k0+1]))));
                u16 hah, hal, hbh_, hbl_; split2(ha, hah, hal); split2(hb, hbh_, hbl_);
                dh[p] = ((u32)hbh_ << 16) | hah;
                dl[p] = ((u32)hbl_ << 16) | hal;
            }
            __builtin_memcpy(&hfh[kt], dh, 16);
            __builtin_memcpy(&hfl[kt], dl, 16);
        }
#pragma unroll
        for (int r = 0; r < 4; ++r) {
            const size_t gr = (size_t)(crow + r) * 3;
            float c0 = in_aux[gr], c1 = in_aux[gr + 1], c2 = in_aux[gr + 2];
            cst[r] = tanh_(fmaf(c0, Wsfc2[unit*3], fmaf(c1, Wsfc2[unit*3+1], fmaf(c2, Wsfc2[unit*3+2], bsfc2[unit]))));
        }
    }

    // x prefetch (lev 59); per-q float4 slices of [main(4) | mem(16)], q==3 zero
    float4 XA = {0,0,0,0}, XB = {0,0,0,0};
    {
        const size_t mi = (size_t)aRow * NLEVS + 59;
        if (q == 0)      { XA = *(const float4*)(in_main + mi * 4);      XB = *(const float4*)(in_mem + mi * 16); }
        else if (q == 1) { XA = *(const float4*)(in_mem + mi * 16 + 4);  XB = *(const float4*)(in_mem + mi * 16 + 8); }
        else if (q == 2) { XA = *(const float4*)(in_mem + mi * 16 + 12); }
    }

#pragma unroll 1
    for (int t = 0; t < NLEVS; ++t) {
        const int lev = 59 - t;
        const int buf = t & 1;
        // x A-frag (single bf16; k>=20 zero-padded to match zeroed W rows)
        bf16x8 ax;
        {
            float xv[8] = {0, 0, 0, 0, 0, 0, 0, 0};
            if (q < 2)       { xv[0]=XA.x; xv[1]=XA.y; xv[2]=XA.z; xv[3]=XA.w; xv[4]=XB.x; xv[5]=XB.y; xv[6]=XB.z; xv[7]=XB.w; }
            else if (q == 2) { xv[0]=XA.x; xv[1]=XA.y; xv[2]=XA.z; xv[3]=XA.w; }
            u32 d[4];
#pragma unroll
            for (int p = 0; p < 4; ++p)
                d[p] = ((u32)f2bf(xv[p*2+1]) << 16) | f2bf(xv[p*2]);
            __builtin_memcpy(&ax, d, 16);
        }
        if (t < 59) {
            const size_t mi = (size_t)aRow * NLEVS + (lev - 1);
            if (q == 0)      { XA = *(const float4*)(in_main + mi * 4);      XB = *(const float4*)(in_mem + mi * 16); }
            else if (q == 1) { XA = *(const float4*)(in_mem + mi * 16 + 4);  XB = *(const float4*)(in_mem + mi * 16 + 8); }
            else if (q == 2) { XA = *(const float4*)(in_mem + mi * 16 + 12); }
        }
        // gates: 8 MFMA each (weights hi/lo, h hi/lo, cross-lo dropped)
        f32x4 C[4];
#pragma unroll
        for (int g = 0; g < 4; ++g) {
            f32x4 a = {bias[g], bias[g], bias[g], bias[g]};
            a = MFMA(ax, Bih_h[g], a);
            a = MFMA(ax, Bih_l[g], a);
#pragma unroll
            for (int kt = 0; kt < 2; ++kt) {
                a = MFMA(hfh[kt], Bhh_h[g][kt], a);
                a = MFMA(hfl[kt], Bhh_h[g][kt], a);
                a = MFMA(hfh[kt], Bhh_l[g][kt], a);
            }
            C[g] = a;
        }
#pragma unroll
        for (int r = 0; r < 4; ++r) {
            float h = gate_act(C[0][r], C[1][r], C[2][r], C[3][r], cst[r]);
            u16 hh_, hl_; split2(h, hh_, hl_);
            hbh[buf][q * 4 + r][unit] = hh_;
            hbl[buf][q * 4 + r][unit] = hl_;
        }
        __syncthreads();   // one barrier/step; double buffer protects overwrites
        // LDS planes ARE the A-frags: direct 16B reads; r1 stores hi plane only
#pragma unroll
        for (int kt = 0; kt < 2; ++kt) {
            hfh[kt] = *(const bf16x8*)&hbh[buf][l15][kt * 32 + q * 8];
            hfl[kt] = *(const bf16x8*)&hbl[buf][l15][kt * 32 + q * 8];
            u32x4 sv; __builtin_memcpy(&sv, &hfh[kt], 16);
            *(u32x4*)(r1 + ((size_t)(lev * 8 + kt * 4 + q) * ch_rows + lloc) * 8) = sv;
        }
    }
}

// ============ Kernel 2: LSTM2 forward (no heads) ============
__global__ __launch_bounds__(256, 2)
void lstm2_kern(const float* __restrict__ in_aux,
                const float* __restrict__ Wtoa1, const float* __restrict__ btoa1,
                const float* __restrict__ Wtoa2, const float* __restrict__ btoa2,
                const float* __restrict__ wsf, const u16* __restrict__ wpk,
                const u16* __restrict__ r1, u16* __restrict__ r2,
                int b_off, int ch_rows)
{
    __shared__ __align__(16) u16 hbh[2][16][72];
    __shared__ __align__(16) u16 hbl[2][16][72];
    const int tid = threadIdx.x;
    const int lane = tid & 63, wv = tid >> 6;
    const int q = lane >> 4, l15 = lane & 15;
    const int lloc = blockIdx.x * 16 + l15;
    const int aRow = b_off + lloc;
    const int crow = b_off + blockIdx.x * 16 + q * 4;
    const int unit = wv * 16 + l15;

    bf16x8 Bih_h[4][2], Bih_l[4][2], Bhh_h[4][2], Bhh_l[4][2];
    float bias[4];
#pragma unroll
    for (int g = 0; g < 4; ++g) {
        const int col = g * 64 + unit;
#pragma unroll
        for (int kt = 0; kt < 2; ++kt) {
            Bih_h[g][kt] = *(const bf16x8*)(wpk + W2IH_HI + col * 64 + kt * 32 + q * 8);
            Bih_l[g][kt] = *(const bf16x8*)(wpk + W2IH_LO + col * 64 + kt * 32 + q * 8);
            Bhh_h[g][kt] = *(const bf16x8*)(wpk + W2HH_HI + col * 64 + kt * 32 + q * 8);
            Bhh_l[g][kt] = *(const bf16x8*)(wpk + W2HH_LO + col * 64 + kt * 32 + q * 8);
        }
        bias[g] = wsf[256 + col];
    }

    bf16x8 hfh[2], hfl[2];
    float cst[4];
    {
        const float toa = in_aux[(size_t)aRow * 3 + 1];
#pragma unroll
        for (int kt = 0; kt < 2; ++kt) {
            u32 dh[4], dl[4];
#pragma unroll
            for (int p = 0; p < 4; ++p) {
                int k0 = kt * 32 + q * 8 + p * 2;
                float ha = fmaf(toa, Wtoa2[k0],     btoa2[k0]);
                float hb = fmaf(toa, Wtoa2[k0 + 1], btoa2[k0 + 1]);
                u16 hah, hal, hbh_, hbl_; split2(ha, hah, hal); split2(hb, hbh_, hbl_);
                dh[p] = ((u32)hbh_ << 16) | hah;
                dl[p] = ((u32)hbl_ << 16) | hal;
            }
            __builtin_memcpy(&hfh[kt], dh, 16);
            __builtin_memcpy(&hfl[kt], dl, 16);
        }
#pragma unroll
        for (int r = 0; r < 4; ++r) {
            const float toc = in_aux[(size_t)(crow + r) * 3 + 1];
            cst[r] = fmaf(toc, Wtoa1[unit], btoa1[unit]);
        }
    }

    bf16x8 px[2];
#pragma unroll
    for (int kt = 0; kt < 2; ++kt)
        px[kt] = *(const bf16x8*)(r1 + ((size_t)(0 * 8 + kt * 4 + q) * ch_rows + lloc) * 8);

#pragma unroll 1
    for (int lev = 0; lev < NLEVS; ++lev) {
        const int buf = lev & 1;
        bf16x8 ax[2];
        ax[0] = px[0]; ax[1] = px[1];
        if (lev < 59) {
#pragma unroll
            for (int kt = 0; kt < 2; ++kt)
                px[kt] = *(const bf16x8*)(r1 + ((size_t)((lev + 1) * 8 + kt * 4 + q) * ch_rows + lloc) * 8);
        }
        // gates: 10 MFMA each
        f32x4 C[4];
#pragma unroll
        for (int g = 0; g < 4; ++g) {
            f32x4 a = {bias[g], bias[g], bias[g], bias[g]};
#pragma unroll
            for (int kt = 0; kt < 2; ++kt) {
                a = MFMA(ax[kt], Bih_h[g][kt], a);
                a = MFMA(ax[kt], Bih_l[g][kt], a);
                a = MFMA(hfh[kt], Bhh_h[g][kt], a);
                a = MFMA(hfl[kt], Bhh_h[g][kt], a);
                a = MFMA(hfh[kt], Bhh_l[g][kt], a);
            }
            C[g] = a;
        }
#pragma unroll
        for (int r = 0; r < 4; ++r) {
            float h = gate_act(C[0][r], C[1][r], C[2][r], C[3][r], cst[r]);
            u16 hh_, hl_; split2(h, hh_, hl_);
            hbh[buf][q * 4 + r][unit] = hh_;
            hbl[buf][q * 4 + r][unit] = hl_;
        }
        __syncthreads();
#pragma unroll
        for (int kt = 0; kt < 2; ++kt) {
            hfh[kt] = *(const bf16x8*)&hbh[buf][l15][kt * 32 + q * 8];
            hfl[kt] = *(const bf16x8*)&hbl[buf][l15][kt * 32 + q * 8];
            u32x4 sv; __builtin_memcpy(&sv, &hfh[kt], 16);
            *(u32x4*)(r2 + ((size_t)(lev * 8 + kt * 4 + q) * ch_rows + lloc) * 8) = sv;
        }
    }
}

// ============ Kernel 3: heads — batched GEMM on stored h2 ============
// wave-task = one (rowgrp, lev): 16 rows x 23 head cols, hi/lo weights (8 MFMA).
__global__ __launch_bounds__(256, 4)
void heads_kern(const float* __restrict__ wsf, const u16* __restrict__ wpk,
                const u16* __restrict__ r2, int b_off, int ch_rows, int ntasks,
                float* __restrict__ out)
{
    const int tid = threadIdx.x;
    const int lane = tid & 63, wv = tid >> 6;
    const int q = lane >> 4, l15 = lane & 15;
    const int id = blockIdx.x * 4 + wv;
    if (id >= ntasks) return;
    const int rowgrp = id / NLEVS;
    const int lev = id - rowgrp * NLEVS;
    const int lloc = rowgrp * 16 + l15;

    bf16x8 hf[2];
#pragma unroll
    for (int kt = 0; kt < 2; ++kt)
        hf[kt] = *(const bf16x8*)(r2 + ((size_t)(lev * 8 + kt * 4 + q) * ch_rows + lloc) * 8);

#pragma unroll
    for (int tile = 0; tile < 2; ++tile) {
        const int col = tile * 16 + l15;
        const float bh = wsf[512 + col];
        f32x4 a = {bh, bh, bh, bh};
#pragma unroll
        for (int kt = 0; kt < 2; ++kt) {
            const bf16x8 Bh = *(const bf16x8*)(wpk + WHD_HI + col * 64 + kt * 32 + q * 8);
            const bf16x8 Bl = *(const bf16x8*)(wpk + WHD_LO + col * 64 + kt * 32 + q * 8);
            a = MFMA(hf[kt], Bh, a);
            a = MFMA(hf[kt], Bl, a);
        }
#pragma unroll
        for (int r = 0; r < 4; ++r) {
            const size_t gb = (size_t)(b_off + rowgrp * 16 + q * 4 + r);
            if (tile == 0) {
                out[MEM_OFF + (gb * NLEVS + lev) * 16 + l15] = tanh_(a[r]);
            } else {
                if (l15 < 4) out[(gb * NLEVS + lev) * 4 + l15] = a[r];
                else if (l15 < 7 && lev == NLEVS - 1) out[SFC_OFF + gb * 3 + (l15 - 4)] = a[r];
            }
        }
    }
}

extern "C" void kernel_launch(void* const* d_in, const int* in_sizes, int n_in,
                              void* d_out, int out_size, void* d_ws, size_t ws_size,
                              hipStream_t stream) {
    const float* in_main = (const float*)d_in[0];
    const float* in_aux  = (const float*)d_in[1];
    const float* in_mem  = (const float*)d_in[2];
    const float* Wsfc1   = (const float*)d_in[3];
    const float* bsfc1   = (const float*)d_in[4];
    const float* Wsfc2   = (const float*)d_in[5];
    const float* bsfc2   = (const float*)d_in[6];
    const float* Wtoa1   = (const float*)d_in[7];
    const float* btoa1   = (const float*)d_in[8];
    const float* Wtoa2   = (const float*)d_in[9];
    const float* btoa2   = (const float*)d_in[10];
    const float* W1ih    = (const float*)d_in[11];
    const float* W1hh    = (const float*)d_in[12];
    const float* b1ih    = (const float*)d_in[13];
    const float* b1hh    = (const float*)d_in[14];
    const float* W2ih    = (const float*)d_in[15];
    const float* W2hh    = (const float*)d_in[16];
    const float* b2ih    = (const float*)d_in[17];
    const float* b2hh    = (const float*)d_in[18];
    const float* Wlat    = (const float*)d_in[19];
    const float* blat    = (const float*)d_in[20];
    const float* Wout    = (const float*)d_in[21];
    const float* bout    = (const float*)d_in[22];
    const float* Wsfco   = (const float*)d_in[23];
    const float* bsfco   = (const float*)d_in[24];
    float* out           = (float*)d_out;

    float* wsf    = (float*)d_ws;
    u16*   wpk    = (u16*)((char*)d_ws + WPK_BYTE_OFF);
    u16*   rbase  = (u16*)((char*)d_ws + WS_R1_BYTE_OFF);

    setup_pack<<<235, 256, 0, stream>>>(W1ih, W1hh, W2ih, W2hh, Wlat, Wout, Wsfco,
                                        b1ih, b1hh, b2ih, b2hh, blat, bout, bsfco,
                                        wsf, wpk);

    const size_t avail = (ws_size > WS_R1_BYTE_OFF) ? ws_size - WS_R1_BYTE_OFF : 0;
    const size_t per_row = (size_t)NLEVS * 64 * 2 * 2;   // r1 + r2 bf16 = 15360 B/row
    size_t rows = avail / per_row;
    rows &= ~(size_t)15;
    if (rows > BATCH) rows = BATCH;
    if (rows < 16) rows = 16;

    for (int off = 0; off < BATCH; off += (int)rows) {
        int nr = (BATCH - off < (int)rows) ? (BATCH - off) : (int)rows;
        u16* r1 = rbase;
        u16* r2 = rbase + (size_t)NLEVS * nr * 64;
        lstm1_kern<<<nr / 16, 256, 0, stream>>>(
            in_main, in_aux, in_mem, Wsfc1, bsfc1, Wsfc2, bsfc2,
            wsf, wpk, r1, off, nr);
        lstm2_kern<<<nr / 16, 256, 0, stream>>>(
            in_aux, Wtoa1, btoa1, Wtoa2, btoa2,
            wsf, wpk, r1, r2, off, nr);
        const int ntasks = (nr / 16) * NLEVS;
        heads_kern<<<(ntasks + 3) / 4, 256, 0, stream>>>(
            wsf, wpk, r2, off, nr, ntasks, out);
    }
}

// Round 12
// 377.155 us; speedup vs baseline: 1.9779x; 1.2959x over previous
//
#include <hip/hip_runtime.h>
#include <hip/hip_bf16.h>

typedef unsigned short u16;
typedef unsigned int u32;
typedef __attribute__((ext_vector_type(8))) short bf16x8;
typedef __attribute__((ext_vector_type(4))) float f32x4;
typedef __attribute__((ext_vector_type(4))) u32 u32x4;

#define BATCH 16384
#define NLEVS 60

#define SFC_OFF ((size_t)BATCH * NLEVS * 4)
#define MEM_OFF (SFC_OFF + (size_t)BATCH * 3)

// packed u16 plane offsets (in u16 units, from wpk) — layout validated r5-r11
#define W1IH_HI 0
#define W1IH_LO 8192
#define W1HH_HI 16384
#define W1HH_LO 32768
#define W2IH_HI 49152
#define W2IH_LO 65536
#define W2HH_HI 81920
#define W2HH_LO 98304
#define WHD_HI  114688
#define WHD_LO  116736

#define WPK_BYTE_OFF 4096
#define WS_R1_BYTE_OFF 262144

// gate prescale: i,f,o by -log2(e) (sigmoid), g by +2*log2(e) (tanh)
#define SIGK -1.4426950408889634f
#define TANK  2.8853900817779268f

#define MFMA(a, b, c) __builtin_amdgcn_mfma_f32_16x16x32_bf16((a), (b), (c), 0, 0, 0)

__device__ __forceinline__ float bf2f(u16 u) {
    union { u32 i; float f; } v; v.i = (u32)u << 16; return v.f;
}
__device__ __forceinline__ u16 f2bf(float f) {
    __hip_bfloat16 b = __float2bfloat16(f);
    u16 u; __builtin_memcpy(&u, &b, 2); return u;
}
__device__ __forceinline__ void split2(float w, u16& hi, u16& lo) {
    u16 h = f2bf(w);
    hi = h;
    lo = f2bf(w - bf2f(h));
}
__device__ __forceinline__ float tanh_(float x) {
    float ax = fabsf(x);
    float e  = __builtin_amdgcn_exp2f(-TANK * ax);
    float t  = (1.0f - e) * __builtin_amdgcn_rcpf(1.0f + e);
    return copysignf(t, x);
}

// Pack all weights to bf16 hi/lo planes with gate prescale; fuse biases and
// Wout@Wlat head (heads unscaled). Validated r5-r11.
__global__ void setup_pack(const float* __restrict__ W1ih, const float* __restrict__ W1hh,
                           const float* __restrict__ W2ih, const float* __restrict__ W2hh,
                           const float* __restrict__ Wlat, const float* __restrict__ Wout,
                           const float* __restrict__ Wsfco,
                           const float* __restrict__ b1ih, const float* __restrict__ b1hh,
                           const float* __restrict__ b2ih, const float* __restrict__ b2hh,
                           const float* __restrict__ blat, const float* __restrict__ bout,
                           const float* __restrict__ bsfco,
                           float* __restrict__ wsf, u16* __restrict__ wpk)
{
    int t = blockIdx.x * 256 + threadIdx.x;
    if (t < 256) {
        float sc = ((t >> 6) == 2) ? TANK : SIGK;
        wsf[t] = (b1ih[t] + b1hh[t]) * sc; return;
    }
    if (t < 512) {
        int j = t - 256;
        float sc = ((j >> 6) == 2) ? TANK : SIGK;
        wsf[256 + j] = (b2ih[j] + b2hh[j]) * sc; return;
    }
    if (t < 544) {
        int j = t - 512; float v;
        if (j < 16) v = blat[j];
        else if (j < 20) { v = bout[j - 16]; for (int m = 0; m < 16; ++m) v += Wout[(j - 16) * 16 + m] * blat[m]; }
        else if (j < 23) v = bsfco[j - 20];
        else v = 0.f;
        wsf[512 + j] = v; return;
    }
    int u = t - 544;
    float w; int hi_off, lo_off, idx, gate = -1;
    if (u < 8192) {
        int col = u >> 5, k = u & 31;
        w = (k < 20) ? W1ih[col * 20 + k] : 0.f;
        hi_off = W1IH_HI; lo_off = W1IH_LO; idx = u; gate = col >> 6;
    } else if (u < 24576) {
        idx = u - 8192; w = W1hh[idx]; hi_off = W1HH_HI; lo_off = W1HH_LO; gate = idx >> 12;
    } else if (u < 40960) {
        idx = u - 24576; w = W2ih[idx]; hi_off = W2IH_HI; lo_off = W2IH_LO; gate = idx >> 12;
    } else if (u < 57344) {
        idx = u - 40960; w = W2hh[idx]; hi_off = W2HH_HI; lo_off = W2HH_LO; gate = idx >> 12;
    } else if (u < 59392) {
        idx = u - 57344; int hc = idx >> 6, k = idx & 63;
        if (hc < 16) w = Wlat[hc * 64 + k];
        else if (hc < 20) { w = 0.f; for (int m = 0; m < 16; ++m) w += Wout[(hc - 16) * 16 + m] * Wlat[m * 64 + k]; }
        else if (hc < 23) w = Wsfco[(hc - 20) * 64 + k];
        else w = 0.f;
        hi_off = WHD_HI; lo_off = WHD_LO;
    } else return;
    if (gate >= 0) w *= (gate == 2) ? TANK : SIGK;
    u16 h_, l_; split2(w, h_, l_);
    wpk[hi_off + idx] = h_;
    wpk[lo_off + idx] = l_;
}

// Fused gate epilogue (prescaled pre-activations). Validated r8-r11.
__device__ __forceinline__ float gate_act(float si, float sf, float sg, float so, float& c) {
    float ei = __builtin_amdgcn_exp2f(si);
    float ef = __builtin_amdgcn_exp2f(sf);
    float eo = __builtin_amdgcn_exp2f(so);
    float eg = __builtin_amdgcn_exp2f(-fabsf(sg));
    float p2 = copysignf(1.f - eg, sg) * __builtin_amdgcn_rcpf((1.f + ei) * (1.f + eg));
    c = fmaf(__builtin_amdgcn_rcpf(1.f + ef), c, p2);
    float ec = __builtin_amdgcn_exp2f(-fabsf(TANK * c));
    return copysignf(1.f - ec, c) * __builtin_amdgcn_rcpf((1.f + eo) * (1.f + ec));
}

// ============ xcvt: pre-convert x to bf16 [row][lev][24] (k 20..23 = 0) ======
// thread = one 16B q-slice (q in 0..2); writes coalesced (48B per (row,lev)).
__global__ __launch_bounds__(256)
void xcvt_kern(const float* __restrict__ in_main, const float* __restrict__ in_mem,
               u16* __restrict__ xb, int b_off, int njobs)
{
    int t = blockIdx.x * 256 + threadIdx.x;
    if (t >= njobs) return;
    const int q = t % 3;
    const int rl = t / 3;
    const int lev = rl % NLEVS;
    const int row = rl / NLEVS;               // chunk-local
    const size_t mi = (size_t)(b_off + row) * NLEVS + lev;
    float v[8];
    if (q == 0) {
        float4 a = *(const float4*)(in_main + mi * 4);
        float4 b = *(const float4*)(in_mem + mi * 16);
        v[0]=a.x; v[1]=a.y; v[2]=a.z; v[3]=a.w; v[4]=b.x; v[5]=b.y; v[6]=b.z; v[7]=b.w;
    } else if (q == 1) {
        float4 a = *(const float4*)(in_mem + mi * 16 + 4);
        float4 b = *(const float4*)(in_mem + mi * 16 + 8);
        v[0]=a.x; v[1]=a.y; v[2]=a.z; v[3]=a.w; v[4]=b.x; v[5]=b.y; v[6]=b.z; v[7]=b.w;
    } else {
        float4 a = *(const float4*)(in_mem + mi * 16 + 12);
        v[0]=a.x; v[1]=a.y; v[2]=a.z; v[3]=a.w; v[4]=0; v[5]=0; v[6]=0; v[7]=0;
    }
    u32 d[4];
#pragma unroll
    for (int p = 0; p < 4; ++p)
        d[p] = ((u32)f2bf(v[p*2+1]) << 16) | f2bf(v[p*2]);
    *(u32x4*)(xb + ((size_t)row * NLEVS + lev) * 24 + q * 8) = *(const u32x4*)d;
}

// ============ Kernel 1: LSTM1 (reversed levels), 2 tiles/wave ============
// Block = 32 rows (tiles A/B of 16); 4 waves; wave owns 16 units x 4 gates.
// Weights hi/lo resident; recurrent h hi/lo via direct-frag LDS planes.
__global__ __launch_bounds__(256, 2)
void lstm1_kern(const u16* __restrict__ xb, const float* __restrict__ in_aux,
                const float* __restrict__ Wsfc1, const float* __restrict__ bsfc1,
                const float* __restrict__ Wsfc2, const float* __restrict__ bsfc2,
                const float* __restrict__ wsf, const u16* __restrict__ wpk,
                u16* __restrict__ r1, int b_off, int ch_rows)
{
    __shared__ __align__(16) u16 hAh[2][16][72], hAl[2][16][72];
    __shared__ __align__(16) u16 hBh[2][16][72], hBl[2][16][72];
    const int tid = threadIdx.x;
    const int lane = tid & 63, wv = tid >> 6;
    const int q = lane >> 4, l15 = lane & 15;
    const int llocA = blockIdx.x * 32 + l15;
    const int llocB = llocA + 16;
    const int aRowA = b_off + llocA;
    const int aRowB = b_off + llocB;
    const int crowA = b_off + blockIdx.x * 32 + q * 4;
    const int crowB = crowA + 16;
    const int unit = wv * 16 + l15;

    bf16x8 Bih_h[4], Bih_l[4], Bhh_h[4][2], Bhh_l[4][2];
    float bias[4];
#pragma unroll
    for (int g = 0; g < 4; ++g) {
        const int col = g * 64 + unit;
        Bih_h[g] = *(const bf16x8*)(wpk + W1IH_HI + col * 32 + q * 8);
        Bih_l[g] = *(const bf16x8*)(wpk + W1IH_LO + col * 32 + q * 8);
#pragma unroll
        for (int kt = 0; kt < 2; ++kt) {
            Bhh_h[g][kt] = *(const bf16x8*)(wpk + W1HH_HI + col * 64 + kt * 32 + q * 8);
            Bhh_l[g][kt] = *(const bf16x8*)(wpk + W1HH_LO + col * 64 + kt * 32 + q * 8);
        }
        bias[g] = wsf[col];
    }

    bf16x8 hfhA[2], hflA[2], hfhB[2], hflB[2];
    float cstA[4], cstB[4];

    // ---- init h0/c0 for both tiles
    {
        const float aA0 = in_aux[(size_t)aRowA * 3], aA1 = in_aux[(size_t)aRowA * 3 + 1], aA2 = in_aux[(size_t)aRowA * 3 + 2];
        const float aB0 = in_aux[(size_t)aRowB * 3], aB1 = in_aux[(size_t)aRowB * 3 + 1], aB2 = in_aux[(size_t)aRowB * 3 + 2];
#pragma unroll
        for (int kt = 0; kt < 2; ++kt) {
            u32 dhA[4], dlA[4], dhB[4], dlB[4];
#pragma unroll
            for (int p = 0; p < 4; ++p) {
                int k0 = kt * 32 + q * 8 + p * 2;
                float w0 = Wsfc1[k0*3], w1 = Wsfc1[k0*3+1], w2 = Wsfc1[k0*3+2], bb = bsfc1[k0];
                float w3 = Wsfc1[k0*3+3], w4 = Wsfc1[k0*3+4], w5 = Wsfc1[k0*3+5], bc = bsfc1[k0+1];
                float ha = tanh_(fmaf(aA0, w0, fmaf(aA1, w1, fmaf(aA2, w2, bb))));
                float hb = tanh_(fmaf(aA0, w3, fmaf(aA1, w4, fmaf(aA2, w5, bc))));
                u16 h1, l1, h2, l2; split2(ha, h1, l1); split2(hb, h2, l2);
                dhA[p] = ((u32)h2 << 16) | h1; dlA[p] = ((u32)l2 << 16) | l1;
                ha = tanh_(fmaf(aB0, w0, fmaf(aB1, w1, fmaf(aB2, w2, bb))));
                hb = tanh_(fmaf(aB0, w3, fmaf(aB1, w4, fmaf(aB2, w5, bc))));
                split2(ha, h1, l1); split2(hb, h2, l2);
                dhB[p] = ((u32)h2 << 16) | h1; dlB[p] = ((u32)l2 << 16) | l1;
            }
            __builtin_memcpy(&hfhA[kt], dhA, 16); __builtin_memcpy(&hflA[kt], dlA, 16);
            __builtin_memcpy(&hfhB[kt], dhB, 16); __builtin_memcpy(&hflB[kt], dlB, 16);
        }
#pragma unroll
        for (int r = 0; r < 4; ++r) {
            float w0 = Wsfc2[unit*3], w1 = Wsfc2[unit*3+1], w2 = Wsfc2[unit*3+2], bb = bsfc2[unit];
            const size_t grA = (size_t)(crowA + r) * 3;
            cstA[r] = tanh_(fmaf(in_aux[grA], w0, fmaf(in_aux[grA+1], w1, fmaf(in_aux[grA+2], w2, bb))));
            const size_t grB = (size_t)(crowB + r) * 3;
            cstB[r] = tanh_(fmaf(in_aux[grB], w0, fmaf(in_aux[grB+1], w1, fmaf(in_aux[grB+2], w2, bb))));
        }
    }

    // x prefetch (lev 59): direct bf16 A-frag loads (q==3 -> zero)
    bf16x8 axA = {}, axB = {};
    if (q < 3) {
        axA = *(const bf16x8*)(xb + ((size_t)llocA * NLEVS + 59) * 24 + q * 8);
        axB = *(const bf16x8*)(xb + ((size_t)llocB * NLEVS + 59) * 24 + q * 8);
    }

#pragma unroll 1
    for (int t = 0; t < NLEVS; ++t) {
        const int lev = 59 - t;
        const int buf = t & 1;
        bf16x8 xA = axA, xB = axB;
        if (t < 59 && q < 3) {
            axA = *(const bf16x8*)(xb + ((size_t)llocA * NLEVS + (lev - 1)) * 24 + q * 8);
            axB = *(const bf16x8*)(xb + ((size_t)llocB * NLEVS + (lev - 1)) * 24 + q * 8);
        }
        // gates: two independent 8-deep chains x 4 gates
        f32x4 CA[4], CB[4];
#pragma unroll
        for (int g = 0; g < 4; ++g) {
            f32x4 a = {bias[g], bias[g], bias[g], bias[g]};
            a = MFMA(xA, Bih_h[g], a);
            a = MFMA(xA, Bih_l[g], a);
#pragma unroll
            for (int kt = 0; kt < 2; ++kt) {
                a = MFMA(hfhA[kt], Bhh_h[g][kt], a);
                a = MFMA(hflA[kt], Bhh_h[g][kt], a);
                a = MFMA(hfhA[kt], Bhh_l[g][kt], a);
            }
            CA[g] = a;
            f32x4 b = {bias[g], bias[g], bias[g], bias[g]};
            b = MFMA(xB, Bih_h[g], b);
            b = MFMA(xB, Bih_l[g], b);
#pragma unroll
            for (int kt = 0; kt < 2; ++kt) {
                b = MFMA(hfhB[kt], Bhh_h[g][kt], b);
                b = MFMA(hflB[kt], Bhh_h[g][kt], b);
                b = MFMA(hfhB[kt], Bhh_l[g][kt], b);
            }
            CB[g] = b;
        }
#pragma unroll
        for (int r = 0; r < 4; ++r) {
            float h = gate_act(CA[0][r], CA[1][r], CA[2][r], CA[3][r], cstA[r]);
            u16 hh_, hl_; split2(h, hh_, hl_);
            hAh[buf][q * 4 + r][unit] = hh_;
            hAl[buf][q * 4 + r][unit] = hl_;
            h = gate_act(CB[0][r], CB[1][r], CB[2][r], CB[3][r], cstB[r]);
            split2(h, hh_, hl_);
            hBh[buf][q * 4 + r][unit] = hh_;
            hBl[buf][q * 4 + r][unit] = hl_;
        }
        __syncthreads();
        // direct-frag readback + r1 store (hi plane only)
#pragma unroll
        for (int kt = 0; kt < 2; ++kt) {
            hfhA[kt] = *(const bf16x8*)&hAh[buf][l15][kt * 32 + q * 8];
            hflA[kt] = *(const bf16x8*)&hAl[buf][l15][kt * 32 + q * 8];
            hfhB[kt] = *(const bf16x8*)&hBh[buf][l15][kt * 32 + q * 8];
            hflB[kt] = *(const bf16x8*)&hBl[buf][l15][kt * 32 + q * 8];
            u32x4 svA; __builtin_memcpy(&svA, &hfhA[kt], 16);
            u32x4 svB; __builtin_memcpy(&svB, &hfhB[kt], 16);
            *(u32x4*)(r1 + ((size_t)(lev * 8 + kt * 4 + q) * ch_rows + llocA) * 8) = svA;
            *(u32x4*)(r1 + ((size_t)(lev * 8 + kt * 4 + q) * ch_rows + llocB) * 8) = svB;
        }
    }
}

// ============ Kernel 2: LSTM2 forward + fused heads ============
__global__ __launch_bounds__(256, 2)
void lstm2_kern(const float* __restrict__ in_aux,
                const float* __restrict__ Wtoa1, const float* __restrict__ btoa1,
                const float* __restrict__ Wtoa2, const float* __restrict__ btoa2,
                const float* __restrict__ wsf, const u16* __restrict__ wpk,
                const u16* __restrict__ r1, int b_off, int ch_rows,
                float* __restrict__ out)
{
    __shared__ __align__(16) u16 hbh[2][16][72];
    __shared__ __align__(16) u16 hbl[2][16][72];
    const int tid = threadIdx.x;
    const int lane = tid & 63, wv = tid >> 6;
    const int q = lane >> 4, l15 = lane & 15;
    const int lloc = blockIdx.x * 16 + l15;
    const int aRow = b_off + lloc;
    const int crow = b_off + blockIdx.x * 16 + q * 4;
    const int unit = wv * 16 + l15;

    bf16x8 Bih_h[4][2], Bih_l[4][2], Bhh_h[4][2], Bhh_l[4][2];
    float bias[4];
#pragma unroll
    for (int g = 0; g < 4; ++g) {
        const int col = g * 64 + unit;
#pragma unroll
        for (int kt = 0; kt < 2; ++kt) {
            Bih_h[g][kt] = *(const bf16x8*)(wpk + W2IH_HI + col * 64 + kt * 32 + q * 8);
            Bih_l[g][kt] = *(const bf16x8*)(wpk + W2IH_LO + col * 64 + kt * 32 + q * 8);
            Bhh_h[g][kt] = *(const bf16x8*)(wpk + W2HH_HI + col * 64 + kt * 32 + q * 8);
            Bhh_l[g][kt] = *(const bf16x8*)(wpk + W2HH_LO + col * 64 + kt * 32 + q * 8);
        }
        bias[g] = wsf[256 + col];
    }
    // head frags on waves 0/1 only (tile wv): cols 0-15 = Wlat/mem, 16-31 = out+sfc
    bf16x8 Bhd_h[2], Bhd_l[2];
    float bhd = 0.f;
    if (wv < 2) {
        const int hc = wv * 16 + l15;
#pragma unroll
        for (int kt = 0; kt < 2; ++kt) {
            Bhd_h[kt] = *(const bf16x8*)(wpk + WHD_HI + hc * 64 + kt * 32 + q * 8);
            Bhd_l[kt] = *(const bf16x8*)(wpk + WHD_LO + hc * 64 + kt * 32 + q * 8);
        }
        bhd = wsf[512 + hc];
    }

    bf16x8 hfh[2], hfl[2];
    float cst[4];
    {
        const float toa = in_aux[(size_t)aRow * 3 + 1];
#pragma unroll
        for (int kt = 0; kt < 2; ++kt) {
            u32 dh[4], dl[4];
#pragma unroll
            for (int p = 0; p < 4; ++p) {
                int k0 = kt * 32 + q * 8 + p * 2;
                float ha = fmaf(toa, Wtoa2[k0],     btoa2[k0]);
                float hb = fmaf(toa, Wtoa2[k0 + 1], btoa2[k0 + 1]);
                u16 hah, hal, hbh_, hbl_; split2(ha, hah, hal); split2(hb, hbh_, hbl_);
                dh[p] = ((u32)hbh_ << 16) | hah;
                dl[p] = ((u32)hbl_ << 16) | hal;
            }
            __builtin_memcpy(&hfh[kt], dh, 16);
            __builtin_memcpy(&hfl[kt], dl, 16);
        }
#pragma unroll
        for (int r = 0; r < 4; ++r) {
            const float toc = in_aux[(size_t)(crow + r) * 3 + 1];
            cst[r] = fmaf(toc, Wtoa1[unit], btoa1[unit]);
        }
    }

    bf16x8 px[2];
#pragma unroll
    for (int kt = 0; kt < 2; ++kt)
        px[kt] = *(const bf16x8*)(r1 + ((size_t)(0 * 8 + kt * 4 + q) * ch_rows + lloc) * 8);

#pragma unroll 1
    for (int lev = 0; lev < NLEVS; ++lev) {
        const int buf = lev & 1;
        bf16x8 ax[2];
        ax[0] = px[0]; ax[1] = px[1];
        if (lev < 59) {
#pragma unroll
            for (int kt = 0; kt < 2; ++kt)
                px[kt] = *(const bf16x8*)(r1 + ((size_t)((lev + 1) * 8 + kt * 4 + q) * ch_rows + lloc) * 8);
        }
        f32x4 C[4];
#pragma unroll
        for (int g = 0; g < 4; ++g) {
            f32x4 a = {bias[g], bias[g], bias[g], bias[g]};
#pragma unroll
            for (int kt = 0; kt < 2; ++kt) {
                a = MFMA(ax[kt], Bih_h[g][kt], a);
                a = MFMA(ax[kt], Bih_l[g][kt], a);
                a = MFMA(hfh[kt], Bhh_h[g][kt], a);
                a = MFMA(hfl[kt], Bhh_h[g][kt], a);
                a = MFMA(hfh[kt], Bhh_l[g][kt], a);
            }
            C[g] = a;
        }
#pragma unroll
        for (int r = 0; r < 4; ++r) {
            float h = gate_act(C[0][r], C[1][r], C[2][r], C[3][r], cst[r]);
            u16 hh_, hl_; split2(h, hh_, hl_);
            hbh[buf][q * 4 + r][unit] = hh_;
            hbl[buf][q * 4 + r][unit] = hl_;
        }
        __syncthreads();
#pragma unroll
        for (int kt = 0; kt < 2; ++kt) {
            hfh[kt] = *(const bf16x8*)&hbh[buf][l15][kt * 32 + q * 8];
            hfl[kt] = *(const bf16x8*)&hbl[buf][l15][kt * 32 + q * 8];
        }
        // fused heads on fresh h2 (waves 0/1): numerics identical to r11 heads
        if (wv < 2) {
            f32x4 a = {bhd, bhd, bhd, bhd};
#pragma unroll
            for (int kt = 0; kt < 2; ++kt) {
                a = MFMA(hfh[kt], Bhd_h[kt], a);
                a = MFMA(hfh[kt], Bhd_l[kt], a);
            }
#pragma unroll
            for (int r = 0; r < 4; ++r) {
                const size_t gb = (size_t)(crow + r);
                if (wv == 0) {
                    out[MEM_OFF + (gb * NLEVS + lev) * 16 + l15] = tanh_(a[r]);
                } else {
                    if (l15 < 4) out[(gb * NLEVS + lev) * 4 + l15] = a[r];
                    else if (l15 < 7 && lev == NLEVS - 1) out[SFC_OFF + gb * 3 + (l15 - 4)] = a[r];
                }
            }
        }
    }
}

extern "C" void kernel_launch(void* const* d_in, const int* in_sizes, int n_in,
                              void* d_out, int out_size, void* d_ws, size_t ws_size,
                              hipStream_t stream) {
    const float* in_main = (const float*)d_in[0];
    const float* in_aux  = (const float*)d_in[1];
    const float* in_mem  = (const float*)d_in[2];
    const float* Wsfc1   = (const float*)d_in[3];
    const float* bsfc1   = (const float*)d_in[4];
    const float* Wsfc2   = (const float*)d_in[5];
    const float* bsfc2   = (const float*)d_in[6];
    const float* Wtoa1   = (const float*)d_in[7];
    const float* btoa1   = (const float*)d_in[8];
    const float* Wtoa2   = (const float*)d_in[9];
    const float* btoa2   = (const float*)d_in[10];
    const float* W1ih    = (const float*)d_in[11];
    const float* W1hh    = (const float*)d_in[12];
    const float* b1ih    = (const float*)d_in[13];
    const float* b1hh    = (const float*)d_in[14];
    const float* W2ih    = (const float*)d_in[15];
    const float* W2hh    = (const float*)d_in[16];
    const float* b2ih    = (const float*)d_in[17];
    const float* b2hh    = (const float*)d_in[18];
    const float* Wlat    = (const float*)d_in[19];
    const float* blat    = (const float*)d_in[20];
    const float* Wout    = (const float*)d_in[21];
    const float* bout    = (const float*)d_in[22];
    const float* Wsfco   = (const float*)d_in[23];
    const float* bsfco   = (const float*)d_in[24];
    float* out           = (float*)d_out;

    float* wsf    = (float*)d_ws;
    u16*   wpk    = (u16*)((char*)d_ws + WPK_BYTE_OFF);
    u16*   rbase  = (u16*)((char*)d_ws + WS_R1_BYTE_OFF);

    setup_pack<<<235, 256, 0, stream>>>(W1ih, W1hh, W2ih, W2hh, Wlat, Wout, Wsfco,
                                        b1ih, b1hh, b2ih, b2hh, blat, bout, bsfco,
                                        wsf, wpk);

    const size_t avail = (ws_size > WS_R1_BYTE_OFF) ? ws_size - WS_R1_BYTE_OFF : 0;
    // per row: xb = 60*24*2 = 2880 B, r1 = 60*64*2 = 7680 B
    const size_t per_row = 2880 + 7680;
    size_t rows = avail / per_row;
    rows &= ~(size_t)31;
    if (rows > BATCH) rows = BATCH;
    if (rows < 32) rows = 32;

    for (int off = 0; off < BATCH; off += (int)rows) {
        int nr = (BATCH - off < (int)rows) ? (BATCH - off) : (int)rows;
        u16* xb = rbase;
        u16* r1 = rbase + (size_t)nr * NLEVS * 24;
        const int njobs = nr * NLEVS * 3;
        xcvt_kern<<<(njobs + 255) / 256, 256, 0, stream>>>(in_main, in_mem, xb, off, njobs);
        lstm1_kern<<<nr / 32, 256, 0, stream>>>(
            xb, in_aux, Wsfc1, bsfc1, Wsfc2, bsfc2, wsf, wpk, r1, off, nr);
        lstm2_kern<<<nr / 16, 256, 0, stream>>>(
            in_aux, Wtoa1, btoa1, Wtoa2, btoa2, wsf, wpk, r1, off, nr, out);
    }
}